// Round 5
// baseline (439.077 us; speedup 1.0000x reference)
//
#include <hip/hip_runtime.h>
#include <cstdint>

#define NN 100000      // nodes
#define NE 1600000     // edges
#define NG 512         // graphs
#define NP 100032      // NN padded to 64*1563
#define NBLK 391       // ceil(NN/256) for scan kernels
#define NSLICE 12500   // NN / 8  (per-XCD dst slice)
#define VOCAB 10000

typedef unsigned short u16;
typedef u16    u16x8  __attribute__((ext_vector_type(8)));
typedef __bf16 bf16x8 __attribute__((ext_vector_type(8)));
typedef float  f32x4  __attribute__((ext_vector_type(4)));

__device__ __forceinline__ u16 f2bf(float f) {  // RNE, inputs are normal floats
    unsigned u = __float_as_uint(f);
    unsigned r = ((u >> 16) & 1u) + 0x7FFFu;
    return (u16)((u + r) >> 16);
}
__device__ __forceinline__ float bf2f(u16 h) {
    return __uint_as_float(((unsigned)h) << 16);
}

// monotone float->uint encoding so unsigned atomicMax == float max
__device__ __forceinline__ unsigned encF(float f) {
    unsigned s = __float_as_uint(f);
    return (s & 0x80000000u) ? ~s : (s | 0x80000000u);
}
__device__ __forceinline__ float decF(unsigned m) {
    unsigned s = (m & 0x80000000u) ? (m ^ 0x80000000u) : ~m;
    return __uint_as_float(s);
}

__global__ void k_init_outmax(unsigned* __restrict__ om) {
    int i = blockIdx.x * blockDim.x + threadIdx.x;
    if (i < NG * 64) om[i] = 0x007FFFFFu;  // encF(-inf)
}

// fp32 embedding table -> bf16 (1.25 MB, L2-resident everywhere)
__global__ void k_embB(const float* __restrict__ emb, u16* __restrict__ embB) {
    int i = blockIdx.x * blockDim.x + threadIdx.x;
    if (i < VOCAB * 64) embB[i] = f2bf(emb[i]);
}

// ---- CSR construction, XCD-partitioned: group g = blockIdx&7 owns dst slice g ----
// nt loads: the edge stream must not evict csr/cursor lines from L2.
__global__ __launch_bounds__(256) void k_count(const int* __restrict__ ei,
                                               int* __restrict__ degi) {
    int g = blockIdx.x & 7, bi = blockIdx.x >> 3;  // 128 blocks per group
    int lo = g * NSLICE;
    const int chunk = NE / 128;  // 12500
    int e0 = bi * chunk, e1 = e0 + chunk;
    for (int e = e0 + threadIdx.x; e < e1; e += 256) {
        int dst = __builtin_nontemporal_load(ei + NE + e);
        if ((unsigned)(dst - lo) < (unsigned)NSLICE) atomicAdd(&degi[dst], 1);
    }
}

__global__ void k_blocksum(const int* __restrict__ degi, int* __restrict__ partial) {
    __shared__ int s[256];
    int i = blockIdx.x * 256 + threadIdx.x;
    s[threadIdx.x] = (i < NN) ? degi[i] : 0;
    __syncthreads();
    for (int d = 128; d > 0; d >>= 1) {
        if (threadIdx.x < d) s[threadIdx.x] += s[threadIdx.x + d];
        __syncthreads();
    }
    if (threadIdx.x == 0) partial[blockIdx.x] = s[0];
}

__global__ __launch_bounds__(512) void k_scanpart(const int* __restrict__ partial,
                                                  int* __restrict__ bases) {
    __shared__ int s[512];
    int t = threadIdx.x;
    s[t] = (t < NBLK) ? partial[t] : 0;
    __syncthreads();
    for (int d = 1; d < 512; d <<= 1) {
        int v = (t >= d) ? s[t - d] : 0;
        __syncthreads();
        s[t] += v;
        __syncthreads();
    }
    if (t < NBLK) bases[t] = (t == 0) ? 0 : s[t - 1];
}

__global__ void k_offsets(const int* __restrict__ degi, const int* __restrict__ bases,
                          int* __restrict__ off) {
    __shared__ int s[256];
    int t = threadIdx.x, i = blockIdx.x * 256 + t;
    int d = (i < NN) ? degi[i] : 0;
    s[t] = d;
    __syncthreads();
    for (int dd = 1; dd < 256; dd <<= 1) {
        int v = (t >= dd) ? s[t - dd] : 0;
        __syncthreads();
        s[t] += v;
        __syncthreads();
    }
    if (i < NN) off[i] = bases[blockIdx.x] + s[t] - d;  // exclusive
    if (blockIdx.x == gridDim.x - 1 && t == 255) off[NN] = NE;
}

// csr entry = src | (x[src] << 17): src<2^17, x<2^14
__global__ __launch_bounds__(256) void k_fill(const int* __restrict__ ei,
                                              const int* __restrict__ x,
                                              const int* __restrict__ off,
                                              int* __restrict__ cur,
                                              int* __restrict__ csr) {
    int g = blockIdx.x & 7, bi = blockIdx.x >> 3;
    int lo = g * NSLICE;
    const int chunk = NE / 128;
    int e0 = bi * chunk, e1 = e0 + chunk;
    for (int e = e0 + threadIdx.x; e < e1; e += 256) {
        int dst = __builtin_nontemporal_load(ei + NE + e);
        if ((unsigned)(dst - lo) < (unsigned)NSLICE) {
            int src = __builtin_nontemporal_load(ei + e);
            int pos = off[dst] + atomicAdd(&cur[dst], 1);
            csr[pos] = src | (x[src] << 17);
        }
    }
}

// ---- weight prep: fp32 concat -> bf16 packed in B-fragment order ----
__global__ void k_prepW(const float* __restrict__ Wa, const float* __restrict__ Wb,
                        int mode, u16* __restrict__ Wpk) {
    int idx = blockIdx.x * blockDim.x + threadIdx.x;  // 0..2047
    if (idx >= 2048) return;
    int fid = idx >> 6, lane = idx & 63;
    int cT = fid >> 2, ks = fid & 3;
    int quad = lane >> 4, l16 = lane & 15;
    int n = cT * 16 + l16;
    u16x8 v;
    #pragma unroll
    for (int j = 0; j < 8; ++j) {
        int k = ks * 32 + quad * 8 + j;
        float f = (mode == 0) ? (k < 64 ? Wa[k * 128 + n] : Wb[(k - 64) * 128 + n])
                              : (n < 64 ? Wa[k * 64 + n] : Wb[k * 64 + (n - 64)]);
        v[j] = f2bf(f);
    }
    *(u16x8*)(Wpk + idx * 8) = v;
}

// ---- gather-mean of emb[x[src]] into cols 0..63 of A1; own emb into 64..127 ----
__global__ __launch_bounds__(256) void k_gather1(const int* __restrict__ off,
                                                 const int* __restrict__ csr,
                                                 const int* __restrict__ x,
                                                 const u16* __restrict__ embB,
                                                 u16* __restrict__ A1) {
    int wid = (blockIdx.x * blockDim.x + threadIdx.x) >> 6;  // node
    int lane = threadIdx.x & 63;
    if (wid >= NN) return;
    int beg = off[wid], end = off[wid + 1];
    float acc = 0.0f;
    for (int base = beg; base < end; base += 64) {
        int n = min(64, end - base);
        int s = (lane < n) ? csr[base + lane] : 0;
        int j = 0;
        for (; j + 1 < n; j += 2) {
            int p0 = __builtin_amdgcn_readlane(s, j);
            int p1 = __builtin_amdgcn_readlane(s, j + 1);
            float v0 = bf2f(embB[(p0 >> 17) * 64 + lane]);
            float v1 = bf2f(embB[(p1 >> 17) * 64 + lane]);
            acc += v0 + v1;
        }
        if (j < n) {
            int p0 = __builtin_amdgcn_readlane(s, j);
            acc += bf2f(embB[(p0 >> 17) * 64 + lane]);
        }
    }
    A1[wid * 128 + lane] = f2bf(acc / fmaxf((float)(end - beg), 1.0f));
    A1[wid * 128 + 64 + lane] = embB[x[wid] * 64 + lane];  // fused k_embed
}

// ---- GEMM1: H1 = relu(A1[NPx128] @ Wpk1[128x128] + b1), bf16 out ----
__global__ __launch_bounds__(256) void k_gemm1(const u16* __restrict__ A1,
                                               const u16* __restrict__ Wpk,
                                               const float* __restrict__ b1,
                                               u16* __restrict__ H1) {
    int w = threadIdx.x >> 6, lane = threadIdx.x & 63;
    int quad = lane >> 4, l16 = lane & 15;
    u16x8 bfr[2][4];
    #pragma unroll
    for (int ct = 0; ct < 2; ++ct)
        #pragma unroll
        for (int ks = 0; ks < 4; ++ks) {
            int fid = (w * 2 + ct) * 4 + ks;
            bfr[ct][ks] = *(const u16x8*)(Wpk + (fid * 64 + lane) * 8);
        }
    int r0 = blockIdx.x * 64;
    #pragma unroll
    for (int rt = 0; rt < 4; ++rt) {
        int row = r0 + rt * 16 + l16;
        u16x8 a[4];
        #pragma unroll
        for (int ks = 0; ks < 4; ++ks)
            a[ks] = *(const u16x8*)(A1 + row * 128 + ks * 32 + quad * 8);
        #pragma unroll
        for (int ct = 0; ct < 2; ++ct) {
            f32x4 acc = {0.f, 0.f, 0.f, 0.f};
            #pragma unroll
            for (int ks = 0; ks < 4; ++ks)
                acc = __builtin_amdgcn_mfma_f32_16x16x32_bf16(
                    __builtin_bit_cast(bf16x8, a[ks]),
                    __builtin_bit_cast(bf16x8, bfr[ct][ks]), acc, 0, 0, 0);
            int col = w * 32 + ct * 16 + l16;
            float bias = b1[col];
            int gr = r0 + rt * 16 + quad * 4;
            #pragma unroll
            for (int reg = 0; reg < 4; ++reg)
                H1[(gr + reg) * 128 + col] = f2bf(fmaxf(acc[reg] + bias, 0.f));
        }
    }
}

// ---- GEMM2: [P|Q] = H1[NPx128] @ Wpk2[128x128], bf16, split outputs ----
__global__ __launch_bounds__(256) void k_gemm2(const u16* __restrict__ H1,
                                               const u16* __restrict__ Wpk,
                                               u16* __restrict__ P,
                                               u16* __restrict__ Q) {
    int w = threadIdx.x >> 6, lane = threadIdx.x & 63;
    int quad = lane >> 4, l16 = lane & 15;
    u16x8 bfr[2][4];
    #pragma unroll
    for (int ct = 0; ct < 2; ++ct)
        #pragma unroll
        for (int ks = 0; ks < 4; ++ks) {
            int fid = (w * 2 + ct) * 4 + ks;
            bfr[ct][ks] = *(const u16x8*)(Wpk + (fid * 64 + lane) * 8);
        }
    int r0 = blockIdx.x * 64;
    #pragma unroll
    for (int rt = 0; rt < 4; ++rt) {
        int row = r0 + rt * 16 + l16;
        u16x8 a[4];
        #pragma unroll
        for (int ks = 0; ks < 4; ++ks)
            a[ks] = *(const u16x8*)(H1 + row * 128 + ks * 32 + quad * 8);
        #pragma unroll
        for (int ct = 0; ct < 2; ++ct) {
            f32x4 acc = {0.f, 0.f, 0.f, 0.f};
            #pragma unroll
            for (int ks = 0; ks < 4; ++ks)
                acc = __builtin_amdgcn_mfma_f32_16x16x32_bf16(
                    __builtin_bit_cast(bf16x8, a[ks]),
                    __builtin_bit_cast(bf16x8, bfr[ct][ks]), acc, 0, 0, 0);
            int col = w * 32 + ct * 16 + l16;
            int gr = r0 + rt * 16 + quad * 4;
            u16* dstT = (col < 64) ? P : Q;
            int c = col & 63;
            #pragma unroll
            for (int reg = 0; reg < 4; ++reg)
                dstT[(gr + reg) * 64 + c] = f2bf(acc[reg]);
        }
    }
}

// ---- final: h2 = mean_agg(P) + b2 + Q, segment-max into om ----
__global__ __launch_bounds__(256) void k_final(const int* __restrict__ off,
                                               const int* __restrict__ csr,
                                               const u16* __restrict__ P,
                                               const u16* __restrict__ Q,
                                               const float* __restrict__ b2,
                                               const int* __restrict__ batch,
                                               unsigned* __restrict__ om) {
    __shared__ float sR[4][64];
    __shared__ int sG[4];
    int wv = threadIdx.x >> 6, lane = threadIdx.x & 63;
    int node = blockIdx.x * 4 + wv;  // NN % 4 == 0, always valid
    int beg = off[node], end = off[node + 1];
    float acc = 0.0f;
    for (int base = beg; base < end; base += 64) {
        int n = min(64, end - base);
        int s = (lane < n) ? csr[base + lane] : 0;
        int j = 0;
        for (; j + 1 < n; j += 2) {
            int p0 = __builtin_amdgcn_readlane(s, j) & 0x1FFFF;
            int p1 = __builtin_amdgcn_readlane(s, j + 1) & 0x1FFFF;
            float v0 = bf2f(P[p0 * 64 + lane]);
            float v1 = bf2f(P[p1 * 64 + lane]);
            acc += v0 + v1;
        }
        if (j < n) {
            int p0 = __builtin_amdgcn_readlane(s, j) & 0x1FFFF;
            acc += bf2f(P[p0 * 64 + lane]);
        }
    }
    float r = acc / fmaxf((float)(end - beg), 1.0f) + b2[lane]
            + bf2f(Q[node * 64 + lane]);
    int g = batch[node];
    sR[wv][lane] = r;
    if (lane == 0) sG[wv] = g;
    __syncthreads();
    bool leader = (wv == 0) || (sG[wv - 1] != g);
    if (leader) {
        float m = r;
        for (int u = wv + 1; u < 4 && sG[u] == g; ++u) m = fmaxf(m, sR[u][lane]);
        atomicMax(&om[g * 64 + lane], encF(m));
    }
}

__global__ void k_decode(const unsigned* __restrict__ om, float* __restrict__ out) {
    int i = blockIdx.x * blockDim.x + threadIdx.x;
    if (i < NG * 64) out[i] = decF(om[i]);
}

extern "C" void kernel_launch(void* const* d_in, const int* in_sizes, int n_in,
                              void* d_out, int out_size, void* d_ws, size_t ws_size,
                              hipStream_t stream) {
    const int*   x     = (const int*)d_in[0];
    const int*   ei    = (const int*)d_in[1];   // [2, NE] flat: src | dst
    const int*   batch = (const int*)d_in[2];
    // d_in[3] = edge_attr, unused by SAGEConv
    const float* emb   = (const float*)d_in[4];
    const float* W1l   = (const float*)d_in[5];
    const float* b1    = (const float*)d_in[6];
    const float* W1r   = (const float*)d_in[7];
    const float* W2l   = (const float*)d_in[8];
    const float* b2    = (const float*)d_in[9];
    const float* W2r   = (const float*)d_in[10];
    float* out = (float*)d_out;

    // workspace layout (bytes). bf16 tables.
    char* p = (char*)d_ws;
    u16* A1   = (u16*)p;               p += (size_t)NP * 128 * 2;  // [agg1 | h0]
    u16* H1   = (u16*)p;               p += (size_t)NP * 128 * 2;
    u16* P    = (u16*)p;               p += (size_t)NP * 64 * 2;
    u16* Q    = (u16*)p;               p += (size_t)NP * 64 * 2;
    int* csr  = (int*)p;               p += (size_t)NE * 4;
    int* off  = (int*)p;               p += (size_t)(NN + 1) * 4;
    int* degi = (int*)p;               p += (size_t)NN * 4;        // also fill cursor
    int* part = (int*)p;               p += 512 * 4;
    int* base = (int*)p;               p += 512 * 4;
    u16* Wpk1 = (u16*)p;               p += 16384 * 2;
    u16* Wpk2 = (u16*)p;               p += 16384 * 2;
    u16* embB = (u16*)p;               p += (size_t)VOCAB * 64 * 2;
    unsigned* om = (unsigned*)p;

    // --- CSR build (XCD-partitioned count/fill, nt edge stream) ---
    hipMemsetAsync(degi, 0, sizeof(int) * NN, stream);
    k_count<<<1024, 256, 0, stream>>>(ei, degi);
    k_blocksum<<<NBLK, 256, 0, stream>>>(degi, part);
    k_scanpart<<<1, 512, 0, stream>>>(part, base);
    k_offsets<<<NBLK, 256, 0, stream>>>(degi, base, off);
    hipMemsetAsync(degi, 0, sizeof(int) * NN, stream);  // reuse as cursor
    k_fill<<<1024, 256, 0, stream>>>(ei, x, off, degi, csr);

    // --- weight/emb prep + init ---
    k_embB<<<(VOCAB * 64 + 255) / 256, 256, 0, stream>>>(emb, embB);
    k_prepW<<<8, 256, 0, stream>>>(W1l, W1r, 0, Wpk1);  // vertical stack [W1l;W1r]
    k_prepW<<<8, 256, 0, stream>>>(W2l, W2r, 1, Wpk2);  // horizontal [W2l|W2r]
    k_init_outmax<<<(NG * 64 + 255) / 256, 256, 0, stream>>>(om);

    // --- layer 1 ---
    k_gather1<<<(NN * 64 + 255) / 256, 256, 0, stream>>>(off, csr, x, embB, A1);
    k_gemm1<<<NP / 64, 256, 0, stream>>>(A1, Wpk1, b1, H1);

    // --- layer 2 (GEMM first, then gather of P fused with segmax) ---
    k_gemm2<<<NP / 64, 256, 0, stream>>>(H1, Wpk2, P, Q);
    k_final<<<NN / 4, 256, 0, stream>>>(off, csr, P, Q, b2, batch, om);

    k_decode<<<(NG * 64 + 255) / 256, 256, 0, stream>>>(om, out);
}

// Round 6
// 356.484 us; speedup vs baseline: 1.2317x; 1.2317x over previous
//
#include <hip/hip_runtime.h>
#include <cstdint>

#define NN 100000      // nodes
#define NE 1600000     // edges
#define NG 512         // graphs
#define NP 100032      // NN padded to 64*1563
#define NBLK 391       // ceil(NN/256) for scan kernels
#define VOCAB 10000
#define NBUK 64        // dst-range buckets
#define BSZ 1563       // nodes per bucket (64*1563 = 100032 >= NN)
#define CAP 28672      // max edges per bucket (avg 25000)
#define TILE 2048

typedef unsigned short u16;
typedef u16    u16x8  __attribute__((ext_vector_type(8)));
typedef __bf16 bf16x8 __attribute__((ext_vector_type(8)));
typedef float  f32x4  __attribute__((ext_vector_type(4)));

__device__ __forceinline__ u16 f2bf(float f) {  // RNE, inputs are normal floats
    unsigned u = __float_as_uint(f);
    unsigned r = ((u >> 16) & 1u) + 0x7FFFu;
    return (u16)((u + r) >> 16);
}
__device__ __forceinline__ float bf2f(u16 h) {
    return __uint_as_float(((unsigned)h) << 16);
}

// monotone float->uint encoding so unsigned atomicMax == float max
__device__ __forceinline__ unsigned encF(float f) {
    unsigned s = __float_as_uint(f);
    return (s & 0x80000000u) ? ~s : (s | 0x80000000u);
}
__device__ __forceinline__ float decF(unsigned m) {
    unsigned s = (m & 0x80000000u) ? (m ^ 0x80000000u) : ~m;
    return __uint_as_float(s);
}

__global__ void k_init_outmax(unsigned* __restrict__ om) {
    int i = blockIdx.x * blockDim.x + threadIdx.x;
    if (i < NG * 64) om[i] = 0x007FFFFFu;  // encF(-inf)
}

// fp32 embedding table -> bf16 (1.25 MB, cache-resident everywhere)
__global__ void k_embB(const float* __restrict__ emb, u16* __restrict__ embB) {
    int i = blockIdx.x * blockDim.x + threadIdx.x;
    if (i < VOCAB * 64) embB[i] = f2bf(emb[i]);
}

// ---- pass 1: partition edges into 64 dst-range buckets (LDS counting sort/tile) ----
// entry = dstlocal(11) | src(17)
__global__ __launch_bounds__(256) void k_bucket(const int* __restrict__ ei,
                                                int* __restrict__ gcur,
                                                unsigned* __restrict__ gbuf) {
    __shared__ int cnt[NBUK];
    __shared__ int start[NBUK];
    __shared__ int gbase[NBUK];
    __shared__ unsigned buf[TILE];
    __shared__ unsigned char bkt[TILE];
    const int t = threadIdx.x;
    const int e0 = blockIdx.x * (NE / 256);   // 6250 edges per block
    const int e1 = e0 + (NE / 256);
    for (int tb = e0; tb < e1; tb += TILE) {
        const int tc = min(TILE, e1 - tb);
        if (t < NBUK) cnt[t] = 0;
        __syncthreads();
        // phase A: load + rank within tile
        unsigned ent[TILE / 256];
        unsigned char eb[TILE / 256];
        u16 rk[TILE / 256];
        int nm = 0;
        for (int i = t; i < tc; i += 256) {
            int dst = ei[NE + tb + i];
            int src = ei[tb + i];
            unsigned b = (unsigned)dst / BSZ;
            unsigned dl = (unsigned)dst - b * BSZ;
            ent[nm] = (dl << 17) | (unsigned)src;
            eb[nm] = (unsigned char)b;
            rk[nm] = (u16)atomicAdd(&cnt[b], 1);
            ++nm;
        }
        __syncthreads();
        // phase B: exclusive scan of 64 counts
        if (t == 0) {
            int s = 0;
            for (int b = 0; b < NBUK; ++b) { start[b] = s; s += cnt[b]; }
        }
        __syncthreads();
        // phase C: place into bucket-sorted LDS buffer
        for (int k = 0; k < nm; ++k) {
            int pos = start[eb[k]] + rk[k];
            buf[pos] = ent[k];
            bkt[pos] = eb[k];
        }
        // phase D: reserve global space per bucket
        if (t < NBUK) gbase[t] = atomicAdd(&gcur[t], cnt[t]);
        __syncthreads();
        // phase E: coalesced flush
        for (int i = t; i < tc; i += 256) {
            unsigned b = bkt[i];
            gbuf[(size_t)b * CAP + gbase[b] + (i - start[b])] = buf[i];
        }
        __syncthreads();
    }
}

// ---- pass 2a: per-bucket degree histogram -> degi ----
__global__ __launch_bounds__(256) void k_countB(const unsigned* __restrict__ gbuf,
                                                const int* __restrict__ gcur,
                                                int* __restrict__ degi) {
    __shared__ int hist[BSZ];
    int b = blockIdx.x & 63, sub = blockIdx.x >> 6;  // 4 sub-blocks, same XCD slot
    for (int i = threadIdx.x; i < BSZ; i += 256) hist[i] = 0;
    __syncthreads();
    int size = gcur[b];
    int q0 = (size * sub) >> 2, q1 = (size * (sub + 1)) >> 2;
    const unsigned* base = gbuf + (size_t)b * CAP;
    for (int i = q0 + threadIdx.x; i < q1; i += 256)
        atomicAdd(&hist[base[i] >> 17], 1);
    __syncthreads();
    int g0 = b * BSZ;
    for (int i = threadIdx.x; i < BSZ; i += 256) {
        int h = hist[i];
        if (h && g0 + i < NN) atomicAdd(&degi[g0 + i], h);
    }
}

__global__ void k_blocksum(const int* __restrict__ degi, int* __restrict__ partial) {
    __shared__ int s[256];
    int i = blockIdx.x * 256 + threadIdx.x;
    s[threadIdx.x] = (i < NN) ? degi[i] : 0;
    __syncthreads();
    for (int d = 128; d > 0; d >>= 1) {
        if (threadIdx.x < d) s[threadIdx.x] += s[threadIdx.x + d];
        __syncthreads();
    }
    if (threadIdx.x == 0) partial[blockIdx.x] = s[0];
}

__global__ __launch_bounds__(512) void k_scanpart(const int* __restrict__ partial,
                                                  int* __restrict__ bases) {
    __shared__ int s[512];
    int t = threadIdx.x;
    s[t] = (t < NBLK) ? partial[t] : 0;
    __syncthreads();
    for (int d = 1; d < 512; d <<= 1) {
        int v = (t >= d) ? s[t - d] : 0;
        __syncthreads();
        s[t] += v;
        __syncthreads();
    }
    if (t < NBLK) bases[t] = (t == 0) ? 0 : s[t - 1];
}

__global__ void k_offsets(const int* __restrict__ degi, const int* __restrict__ bases,
                          int* __restrict__ off) {
    __shared__ int s[256];
    int t = threadIdx.x, i = blockIdx.x * 256 + t;
    int d = (i < NN) ? degi[i] : 0;
    s[t] = d;
    __syncthreads();
    for (int dd = 1; dd < 256; dd <<= 1) {
        int v = (t >= dd) ? s[t - dd] : 0;
        __syncthreads();
        s[t] += v;
        __syncthreads();
    }
    if (i < NN) off[i] = bases[blockIdx.x] + s[t] - d;  // exclusive
    if (blockIdx.x == gridDim.x - 1 && t == 255) off[NN] = NE;
}

__global__ void k_cpoff(const int* __restrict__ off, int* __restrict__ cur) {
    int i = blockIdx.x * blockDim.x + threadIdx.x;
    if (i < NN) cur[i] = off[i];
}

// ---- pass 2b: fill csr from buckets; csr entry = src | (x[src] << 17) ----
__global__ __launch_bounds__(256) void k_fillB(const unsigned* __restrict__ gbuf,
                                               const int* __restrict__ gcur,
                                               const int* __restrict__ x,
                                               int* __restrict__ cur,
                                               int* __restrict__ csr) {
    int b = blockIdx.x & 63, sub = blockIdx.x >> 6;
    int size = gcur[b];
    int q0 = (size * sub) >> 2, q1 = (size * (sub + 1)) >> 2;
    const unsigned* base = gbuf + (size_t)b * CAP;
    int g0 = b * BSZ;
    for (int i = q0 + threadIdx.x; i < q1; i += 256) {
        unsigned ent = base[i];
        int src = (int)(ent & 0x1FFFFu);
        int dl  = (int)(ent >> 17);
        int pos = atomicAdd(&cur[g0 + dl], 1);
        csr[pos] = src | (x[src] << 17);
    }
}

// ---- weight prep: fp32 concat -> bf16 packed in B-fragment order ----
__global__ void k_prepW(const float* __restrict__ Wa, const float* __restrict__ Wb,
                        int mode, u16* __restrict__ Wpk) {
    int idx = blockIdx.x * blockDim.x + threadIdx.x;  // 0..2047
    if (idx >= 2048) return;
    int fid = idx >> 6, lane = idx & 63;
    int cT = fid >> 2, ks = fid & 3;
    int quad = lane >> 4, l16 = lane & 15;
    int n = cT * 16 + l16;
    u16x8 v;
    #pragma unroll
    for (int j = 0; j < 8; ++j) {
        int k = ks * 32 + quad * 8 + j;
        float f = (mode == 0) ? (k < 64 ? Wa[k * 128 + n] : Wb[(k - 64) * 128 + n])
                              : (n < 64 ? Wa[k * 64 + n] : Wb[k * 64 + (n - 64)]);
        v[j] = f2bf(f);
    }
    *(u16x8*)(Wpk + idx * 8) = v;
}

// ---- gather-mean of emb[x[src]] into cols 0..63 of A1; own emb into 64..127 ----
__global__ __launch_bounds__(256) void k_gather1(const int* __restrict__ off,
                                                 const int* __restrict__ csr,
                                                 const int* __restrict__ x,
                                                 const u16* __restrict__ embB,
                                                 u16* __restrict__ A1) {
    int wid = (blockIdx.x * blockDim.x + threadIdx.x) >> 6;  // node
    int lane = threadIdx.x & 63;
    if (wid >= NN) return;
    int beg = off[wid], end = off[wid + 1];
    float acc = 0.0f;
    for (int base = beg; base < end; base += 64) {
        int n = min(64, end - base);
        int s = (lane < n) ? csr[base + lane] : 0;
        int j = 0;
        for (; j + 1 < n; j += 2) {
            int p0 = __builtin_amdgcn_readlane(s, j);
            int p1 = __builtin_amdgcn_readlane(s, j + 1);
            float v0 = bf2f(embB[(p0 >> 17) * 64 + lane]);
            float v1 = bf2f(embB[(p1 >> 17) * 64 + lane]);
            acc += v0 + v1;
        }
        if (j < n) {
            int p0 = __builtin_amdgcn_readlane(s, j);
            acc += bf2f(embB[(p0 >> 17) * 64 + lane]);
        }
    }
    A1[wid * 128 + lane] = f2bf(acc / fmaxf((float)(end - beg), 1.0f));
    A1[wid * 128 + 64 + lane] = embB[x[wid] * 64 + lane];  // fused k_embed
}

// ---- GEMM1: H1 = relu(A1[NPx128] @ Wpk1[128x128] + b1), bf16 out ----
__global__ __launch_bounds__(256) void k_gemm1(const u16* __restrict__ A1,
                                               const u16* __restrict__ Wpk,
                                               const float* __restrict__ b1,
                                               u16* __restrict__ H1) {
    int w = threadIdx.x >> 6, lane = threadIdx.x & 63;
    int quad = lane >> 4, l16 = lane & 15;
    u16x8 bfr[2][4];
    #pragma unroll
    for (int ct = 0; ct < 2; ++ct)
        #pragma unroll
        for (int ks = 0; ks < 4; ++ks) {
            int fid = (w * 2 + ct) * 4 + ks;
            bfr[ct][ks] = *(const u16x8*)(Wpk + (fid * 64 + lane) * 8);
        }
    int r0 = blockIdx.x * 64;
    #pragma unroll
    for (int rt = 0; rt < 4; ++rt) {
        int row = r0 + rt * 16 + l16;
        u16x8 a[4];
        #pragma unroll
        for (int ks = 0; ks < 4; ++ks)
            a[ks] = *(const u16x8*)(A1 + row * 128 + ks * 32 + quad * 8);
        #pragma unroll
        for (int ct = 0; ct < 2; ++ct) {
            f32x4 acc = {0.f, 0.f, 0.f, 0.f};
            #pragma unroll
            for (int ks = 0; ks < 4; ++ks)
                acc = __builtin_amdgcn_mfma_f32_16x16x32_bf16(
                    __builtin_bit_cast(bf16x8, a[ks]),
                    __builtin_bit_cast(bf16x8, bfr[ct][ks]), acc, 0, 0, 0);
            int col = w * 32 + ct * 16 + l16;
            float bias = b1[col];
            int gr = r0 + rt * 16 + quad * 4;
            #pragma unroll
            for (int reg = 0; reg < 4; ++reg)
                H1[(gr + reg) * 128 + col] = f2bf(fmaxf(acc[reg] + bias, 0.f));
        }
    }
}

// ---- GEMM2: [P|Q] = H1[NPx128] @ Wpk2[128x128], bf16, split outputs ----
__global__ __launch_bounds__(256) void k_gemm2(const u16* __restrict__ H1,
                                               const u16* __restrict__ Wpk,
                                               u16* __restrict__ P,
                                               u16* __restrict__ Q) {
    int w = threadIdx.x >> 6, lane = threadIdx.x & 63;
    int quad = lane >> 4, l16 = lane & 15;
    u16x8 bfr[2][4];
    #pragma unroll
    for (int ct = 0; ct < 2; ++ct)
        #pragma unroll
        for (int ks = 0; ks < 4; ++ks) {
            int fid = (w * 2 + ct) * 4 + ks;
            bfr[ct][ks] = *(const u16x8*)(Wpk + (fid * 64 + lane) * 8);
        }
    int r0 = blockIdx.x * 64;
    #pragma unroll
    for (int rt = 0; rt < 4; ++rt) {
        int row = r0 + rt * 16 + l16;
        u16x8 a[4];
        #pragma unroll
        for (int ks = 0; ks < 4; ++ks)
            a[ks] = *(const u16x8*)(H1 + row * 128 + ks * 32 + quad * 8);
        #pragma unroll
        for (int ct = 0; ct < 2; ++ct) {
            f32x4 acc = {0.f, 0.f, 0.f, 0.f};
            #pragma unroll
            for (int ks = 0; ks < 4; ++ks)
                acc = __builtin_amdgcn_mfma_f32_16x16x32_bf16(
                    __builtin_bit_cast(bf16x8, a[ks]),
                    __builtin_bit_cast(bf16x8, bfr[ct][ks]), acc, 0, 0, 0);
            int col = w * 32 + ct * 16 + l16;
            int gr = r0 + rt * 16 + quad * 4;
            u16* dstT = (col < 64) ? P : Q;
            int c = col & 63;
            #pragma unroll
            for (int reg = 0; reg < 4; ++reg)
                dstT[(gr + reg) * 64 + c] = f2bf(acc[reg]);
        }
    }
}

// ---- final: h2 = mean_agg(P) + b2 + Q, segment-max into om ----
__global__ __launch_bounds__(256) void k_final(const int* __restrict__ off,
                                               const int* __restrict__ csr,
                                               const u16* __restrict__ P,
                                               const u16* __restrict__ Q,
                                               const float* __restrict__ b2,
                                               const int* __restrict__ batch,
                                               unsigned* __restrict__ om) {
    __shared__ float sR[4][64];
    __shared__ int sG[4];
    int wv = threadIdx.x >> 6, lane = threadIdx.x & 63;
    int node = blockIdx.x * 4 + wv;  // NN % 4 == 0, always valid
    int beg = off[node], end = off[node + 1];
    float acc = 0.0f;
    for (int base = beg; base < end; base += 64) {
        int n = min(64, end - base);
        int s = (lane < n) ? csr[base + lane] : 0;
        int j = 0;
        for (; j + 1 < n; j += 2) {
            int p0 = __builtin_amdgcn_readlane(s, j) & 0x1FFFF;
            int p1 = __builtin_amdgcn_readlane(s, j + 1) & 0x1FFFF;
            float v0 = bf2f(P[p0 * 64 + lane]);
            float v1 = bf2f(P[p1 * 64 + lane]);
            acc += v0 + v1;
        }
        if (j < n) {
            int p0 = __builtin_amdgcn_readlane(s, j) & 0x1FFFF;
            acc += bf2f(P[p0 * 64 + lane]);
        }
    }
    float r = acc / fmaxf((float)(end - beg), 1.0f) + b2[lane]
            + bf2f(Q[node * 64 + lane]);
    int g = batch[node];
    sR[wv][lane] = r;
    if (lane == 0) sG[wv] = g;
    __syncthreads();
    bool leader = (wv == 0) || (sG[wv - 1] != g);
    if (leader) {
        float m = r;
        for (int u = wv + 1; u < 4 && sG[u] == g; ++u) m = fmaxf(m, sR[u][lane]);
        atomicMax(&om[g * 64 + lane], encF(m));
    }
}

__global__ void k_decode(const unsigned* __restrict__ om, float* __restrict__ out) {
    int i = blockIdx.x * blockDim.x + threadIdx.x;
    if (i < NG * 64) out[i] = decF(om[i]);
}

extern "C" void kernel_launch(void* const* d_in, const int* in_sizes, int n_in,
                              void* d_out, int out_size, void* d_ws, size_t ws_size,
                              hipStream_t stream) {
    const int*   x     = (const int*)d_in[0];
    const int*   ei    = (const int*)d_in[1];   // [2, NE] flat: src | dst
    const int*   batch = (const int*)d_in[2];
    // d_in[3] = edge_attr, unused by SAGEConv
    const float* emb   = (const float*)d_in[4];
    const float* W1l   = (const float*)d_in[5];
    const float* b1    = (const float*)d_in[6];
    const float* W1r   = (const float*)d_in[7];
    const float* W2l   = (const float*)d_in[8];
    const float* b2    = (const float*)d_in[9];
    const float* W2r   = (const float*)d_in[10];
    float* out = (float*)d_out;

    // workspace layout (bytes). bf16 tables.
    char* p = (char*)d_ws;
    u16* A1   = (u16*)p;               p += (size_t)NP * 128 * 2;  // [agg1 | h0]
    u16* H1   = (u16*)p;               p += (size_t)NP * 128 * 2;
    u16* P    = (u16*)p;               p += (size_t)NP * 64 * 2;
    u16* Q    = (u16*)p;               p += (size_t)NP * 64 * 2;
    int* csr  = (int*)p;               p += (size_t)NE * 4;
    unsigned* gbuf = (unsigned*)p;     p += (size_t)NBUK * CAP * 4;
    int* gcur = (int*)p;               p += NBUK * 4;
    int* off  = (int*)p;               p += (size_t)(NN + 1) * 4;
    int* degi = (int*)p;               p += (size_t)NN * 4;
    int* cur  = (int*)p;               p += (size_t)NN * 4;
    int* part = (int*)p;               p += 512 * 4;
    int* base = (int*)p;               p += 512 * 4;
    u16* Wpk1 = (u16*)p;               p += 16384 * 2;
    u16* Wpk2 = (u16*)p;               p += 16384 * 2;
    u16* embB = (u16*)p;               p += (size_t)VOCAB * 64 * 2;
    unsigned* om = (unsigned*)p;

    // --- CSR build via 64-bucket counting sort ---
    hipMemsetAsync(gcur, 0, sizeof(int) * NBUK, stream);
    hipMemsetAsync(degi, 0, sizeof(int) * NN, stream);
    k_bucket<<<256, 256, 0, stream>>>(ei, gcur, gbuf);
    k_countB<<<256, 256, 0, stream>>>(gbuf, gcur, degi);
    k_blocksum<<<NBLK, 256, 0, stream>>>(degi, part);
    k_scanpart<<<1, 512, 0, stream>>>(part, base);
    k_offsets<<<NBLK, 256, 0, stream>>>(degi, base, off);
    k_cpoff<<<NBLK, 256, 0, stream>>>(off, cur);
    k_fillB<<<256, 256, 0, stream>>>(gbuf, gcur, x, cur, csr);

    // --- weight/emb prep + init ---
    k_embB<<<(VOCAB * 64 + 255) / 256, 256, 0, stream>>>(emb, embB);
    k_prepW<<<8, 256, 0, stream>>>(W1l, W1r, 0, Wpk1);  // vertical stack [W1l;W1r]
    k_prepW<<<8, 256, 0, stream>>>(W2l, W2r, 1, Wpk2);  // horizontal [W2l|W2r]
    k_init_outmax<<<(NG * 64 + 255) / 256, 256, 0, stream>>>(om);

    // --- layer 1 ---
    k_gather1<<<(NN * 64 + 255) / 256, 256, 0, stream>>>(off, csr, x, embB, A1);
    k_gemm1<<<NP / 64, 256, 0, stream>>>(A1, Wpk1, b1, H1);

    // --- layer 2 (GEMM first, then gather of P fused with segmax) ---
    k_gemm2<<<NP / 64, 256, 0, stream>>>(H1, Wpk2, P, Q);
    k_final<<<NN / 4, 256, 0, stream>>>(off, csr, P, Q, b2, batch, om);

    k_decode<<<(NG * 64 + 255) / 256, 256, 0, stream>>>(om, out);
}

// Round 7
// 283.514 us; speedup vs baseline: 1.5487x; 1.2574x over previous
//
#include <hip/hip_runtime.h>
#include <cstdint>

#define NN 100000      // nodes
#define NE 1600000     // edges
#define NG 512         // graphs
#define NP 100032      // NN padded to 64*1563
#define VOCAB 10000
#define NBUK 64        // dst-range buckets
#define BSZ 1563       // nodes per bucket (64*1563 = 100032 >= NN)
#define CAP 28672      // max edges per bucket (avg 25000)
#define TILE 2048

typedef unsigned short u16;
typedef u16    u16x8  __attribute__((ext_vector_type(8)));
typedef __bf16 bf16x8 __attribute__((ext_vector_type(8)));
typedef float  f32x4  __attribute__((ext_vector_type(4)));

__device__ __forceinline__ u16 f2bf(float f) {  // RNE
    unsigned u = __float_as_uint(f);
    unsigned r = ((u >> 16) & 1u) + 0x7FFFu;
    return (u16)((u + r) >> 16);
}
__device__ __forceinline__ float bf2f(u16 h) {
    return __uint_as_float(((unsigned)h) << 16);
}

// monotone float->uint encoding so unsigned atomicMax == float max
__device__ __forceinline__ unsigned encF(float f) {
    unsigned s = __float_as_uint(f);
    return (s & 0x80000000u) ? ~s : (s | 0x80000000u);
}
__device__ __forceinline__ float decF(unsigned m) {
    unsigned s = (m & 0x80000000u) ? (m ^ 0x80000000u) : ~m;
    return __uint_as_float(s);
}

// ---- fused prep: embB cast, both weight packs, outmax init ----
__device__ __forceinline__ void prepW_body(const float* __restrict__ Wa,
                                           const float* __restrict__ Wb,
                                           int mode, u16* __restrict__ Wpk, int idx) {
    int fid = idx >> 6, lane = idx & 63;
    int cT = fid >> 2, ks = fid & 3;
    int quad = lane >> 4, l16 = lane & 15;
    int n = cT * 16 + l16;
    u16x8 v;
    #pragma unroll
    for (int j = 0; j < 8; ++j) {
        int k = ks * 32 + quad * 8 + j;
        float f = (mode == 0) ? (k < 64 ? Wa[k * 128 + n] : Wb[(k - 64) * 128 + n])
                              : (n < 64 ? Wa[k * 64 + n] : Wb[k * 64 + (n - 64)]);
        v[j] = f2bf(f);
    }
    *(u16x8*)(Wpk + idx * 8) = v;
}

__global__ __launch_bounds__(256) void k_prep(
        const float* __restrict__ emb, u16* __restrict__ embB,
        const float* __restrict__ W1l, const float* __restrict__ W1r,
        u16* __restrict__ Wpk1,
        const float* __restrict__ W2l, const float* __restrict__ W2r,
        u16* __restrict__ Wpk2, unsigned* __restrict__ om) {
    int bid = blockIdx.x, t = threadIdx.x;
    if (bid < 2500) {
        int i = bid * 256 + t;
        if (i < VOCAB * 64) embB[i] = f2bf(emb[i]);
    } else if (bid < 2508) {
        prepW_body(W1l, W1r, 0, Wpk1, (bid - 2500) * 256 + t);
    } else if (bid < 2516) {
        prepW_body(W2l, W2r, 1, Wpk2, (bid - 2508) * 256 + t);
    } else {
        int i = (bid - 2516) * 256 + t;
        if (i < NG * 64) om[i] = 0x007FFFFFu;  // encF(-inf)
    }
}

// ---- pass 1: partition edges into 64 dst-range buckets (LDS counting sort/tile) ----
// entry = dstlocal(11) | src(17)
__global__ __launch_bounds__(256) void k_bucket(const int* __restrict__ ei,
                                                int* __restrict__ gcur,
                                                unsigned* __restrict__ gbuf) {
    __shared__ int cnt[NBUK];
    __shared__ int start[NBUK];
    __shared__ int gbase[NBUK];
    __shared__ unsigned buf[TILE];
    __shared__ unsigned char bkt[TILE];
    const int t = threadIdx.x;
    const int e0 = blockIdx.x * (NE / 256);   // 6250 edges per block
    const int e1 = e0 + (NE / 256);
    for (int tb = e0; tb < e1; tb += TILE) {
        const int tc = min(TILE, e1 - tb);
        if (t < NBUK) cnt[t] = 0;
        __syncthreads();
        // phase A: load + rank within tile
        unsigned ent[TILE / 256];
        unsigned char eb[TILE / 256];
        u16 rk[TILE / 256];
        int nm = 0;
        for (int i = t; i < tc; i += 256) {
            int dst = ei[NE + tb + i];
            int src = ei[tb + i];
            unsigned b = (unsigned)dst / BSZ;
            unsigned dl = (unsigned)dst - b * BSZ;
            ent[nm] = (dl << 17) | (unsigned)src;
            eb[nm] = (unsigned char)b;
            rk[nm] = (u16)atomicAdd(&cnt[b], 1);
            ++nm;
        }
        __syncthreads();
        // phase B: wave-0 shuffle scan of 64 counts + global reservation
        if (t < 64) {
            int c = cnt[t];
            int s = c;
            #pragma unroll
            for (int d = 1; d < 64; d <<= 1) {
                int v = __shfl_up(s, d, 64);
                if (t >= d) s += v;
            }
            start[t] = s - c;
            gbase[t] = atomicAdd(&gcur[t], c);
        }
        __syncthreads();
        // phase C: place into bucket-sorted LDS buffer
        for (int k = 0; k < nm; ++k) {
            int pos = start[eb[k]] + rk[k];
            buf[pos] = ent[k];
            bkt[pos] = eb[k];
        }
        __syncthreads();
        // phase D: coalesced flush
        for (int i = t; i < tc; i += 256) {
            unsigned b = bkt[i];
            gbuf[(size_t)b * CAP + gbase[b] + (i - start[b])] = buf[i];
        }
        __syncthreads();
    }
}

// ---- pass 2: per-bucket histogram -> scan -> offsets -> fill csr (one block/bucket) ----
// csr entry = src | (x[src] << 17)
__global__ __launch_bounds__(1024) void k_csr(const unsigned* __restrict__ gbuf,
                                              const int* __restrict__ gcur,
                                              const int* __restrict__ x,
                                              int* __restrict__ off,
                                              int* __restrict__ csr) {
    __shared__ int hist[BSZ];
    __shared__ int curL[BSZ];
    __shared__ int sc[1024];
    __shared__ int sb[64];
    const int b = blockIdx.x, t = threadIdx.x;
    for (int i = t; i < BSZ; i += 1024) hist[i] = 0;
    // bucket global base = sum gcur[0..b)
    if (t < 64) sb[t] = (t < b) ? gcur[t] : 0;
    __syncthreads();
    const int size = gcur[b];
    const unsigned* gb = gbuf + (size_t)b * CAP;
    for (int i = t; i < size; i += 1024)
        atomicAdd(&hist[gb[i] >> 17], 1);
    for (int d = 32; d > 0; d >>= 1) {
        if (t < d) sb[t] += sb[t + d];
        __syncthreads();
    }
    const int gbase = sb[0];
    // exclusive scan of hist[0..BSZ): thread t owns elements 2t, 2t+1
    int a0 = (2 * t < BSZ) ? hist[2 * t] : 0;
    int a1 = (2 * t + 1 < BSZ) ? hist[2 * t + 1] : 0;
    sc[t] = a0 + a1;
    __syncthreads();
    for (int d = 1; d < 1024; d <<= 1) {
        int v = (t >= d) ? sc[t - d] : 0;
        __syncthreads();
        sc[t] += v;
        __syncthreads();
    }
    int ex = (t == 0) ? 0 : sc[t - 1];
    if (2 * t < BSZ) hist[2 * t] = ex;
    if (2 * t + 1 < BSZ) hist[2 * t + 1] = ex + a0;
    __syncthreads();
    const int g0 = b * BSZ;
    for (int i = t; i < BSZ; i += 1024) {
        int v = gbase + hist[i];
        curL[i] = v;
        if (g0 + i <= NN) off[g0 + i] = v;  // bucket 63, i=1531 writes off[NN]=NE
    }
    __syncthreads();
    for (int i = t; i < size; i += 1024) {
        unsigned ent = gb[i];
        int src = (int)(ent & 0x1FFFFu);
        int dl  = (int)(ent >> 17);
        int pos = atomicAdd(&curL[dl], 1);
        csr[pos] = src | (x[src] << 17);
    }
}

// ---- gather-mean of emb[x[src]] into cols 0..63 of A1; own emb into 64..127 ----
__global__ __launch_bounds__(256) void k_gather1(const int* __restrict__ off,
                                                 const int* __restrict__ csr,
                                                 const int* __restrict__ x,
                                                 const u16* __restrict__ embB,
                                                 u16* __restrict__ A1) {
    int wid = (blockIdx.x * blockDim.x + threadIdx.x) >> 6;  // node
    int lane = threadIdx.x & 63;
    if (wid >= NN) return;
    int beg = off[wid], end = off[wid + 1];
    float acc = 0.0f;
    for (int base = beg; base < end; base += 64) {
        int n = min(64, end - base);
        int s = (lane < n) ? csr[base + lane] : 0;
        int j = 0;
        for (; j + 3 < n; j += 4) {
            int p0 = __builtin_amdgcn_readlane(s, j);
            int p1 = __builtin_amdgcn_readlane(s, j + 1);
            int p2 = __builtin_amdgcn_readlane(s, j + 2);
            int p3 = __builtin_amdgcn_readlane(s, j + 3);
            float v0 = bf2f(embB[(p0 >> 17) * 64 + lane]);
            float v1 = bf2f(embB[(p1 >> 17) * 64 + lane]);
            float v2 = bf2f(embB[(p2 >> 17) * 64 + lane]);
            float v3 = bf2f(embB[(p3 >> 17) * 64 + lane]);
            acc += (v0 + v1) + (v2 + v3);
        }
        for (; j < n; ++j) {
            int p0 = __builtin_amdgcn_readlane(s, j);
            acc += bf2f(embB[(p0 >> 17) * 64 + lane]);
        }
    }
    A1[wid * 128 + lane] = f2bf(acc / fmaxf((float)(end - beg), 1.0f));
    A1[wid * 128 + 64 + lane] = embB[x[wid] * 64 + lane];  // fused embed
}

// ---- fused GEMM1+GEMM2 through LDS: H1 = relu(A1@W1+b1); [P|Q] = H1@W2 ----
__global__ __launch_bounds__(256) void k_gemm12(
        const u16* __restrict__ A1, const u16* __restrict__ Wpk1,
        const u16* __restrict__ Wpk2, const float* __restrict__ b1,
        u16* __restrict__ P, u16* __restrict__ Q) {
    __shared__ __align__(16) u16 sH1[64][136];  // pad: 272 B row stride, 16B-aligned
    int w = threadIdx.x >> 6, lane = threadIdx.x & 63;
    int quad = lane >> 4, l16 = lane & 15;
    u16x8 bf1[2][4], bf2[2][4];
    #pragma unroll
    for (int ct = 0; ct < 2; ++ct)
        #pragma unroll
        for (int ks = 0; ks < 4; ++ks) {
            int fid = (w * 2 + ct) * 4 + ks;
            bf1[ct][ks] = *(const u16x8*)(Wpk1 + (fid * 64 + lane) * 8);
            bf2[ct][ks] = *(const u16x8*)(Wpk2 + (fid * 64 + lane) * 8);
        }
    int r0 = blockIdx.x * 64;
    // stage 1: H1 tile -> LDS
    #pragma unroll
    for (int rt = 0; rt < 4; ++rt) {
        int row = r0 + rt * 16 + l16;
        u16x8 a[4];
        #pragma unroll
        for (int ks = 0; ks < 4; ++ks)
            a[ks] = *(const u16x8*)(A1 + row * 128 + ks * 32 + quad * 8);
        #pragma unroll
        for (int ct = 0; ct < 2; ++ct) {
            f32x4 acc = {0.f, 0.f, 0.f, 0.f};
            #pragma unroll
            for (int ks = 0; ks < 4; ++ks)
                acc = __builtin_amdgcn_mfma_f32_16x16x32_bf16(
                    __builtin_bit_cast(bf16x8, a[ks]),
                    __builtin_bit_cast(bf16x8, bf1[ct][ks]), acc, 0, 0, 0);
            int col = w * 32 + ct * 16 + l16;
            float bias = b1[col];
            int lr = rt * 16 + quad * 4;
            #pragma unroll
            for (int reg = 0; reg < 4; ++reg)
                sH1[lr + reg][col] = f2bf(fmaxf(acc[reg] + bias, 0.f));
        }
    }
    __syncthreads();
    // stage 2: [P|Q] from LDS H1
    #pragma unroll
    for (int rt = 0; rt < 4; ++rt) {
        u16x8 a[4];
        #pragma unroll
        for (int ks = 0; ks < 4; ++ks)
            a[ks] = *(const u16x8*)(&sH1[rt * 16 + l16][ks * 32 + quad * 8]);
        #pragma unroll
        for (int ct = 0; ct < 2; ++ct) {
            f32x4 acc = {0.f, 0.f, 0.f, 0.f};
            #pragma unroll
            for (int ks = 0; ks < 4; ++ks)
                acc = __builtin_amdgcn_mfma_f32_16x16x32_bf16(
                    __builtin_bit_cast(bf16x8, a[ks]),
                    __builtin_bit_cast(bf16x8, bf2[ct][ks]), acc, 0, 0, 0);
            int col = w * 32 + ct * 16 + l16;
            int gr = r0 + rt * 16 + quad * 4;
            u16* dstT = (col < 64) ? P : Q;
            int c = col & 63;
            #pragma unroll
            for (int reg = 0; reg < 4; ++reg)
                dstT[(gr + reg) * 64 + c] = f2bf(acc[reg]);
        }
    }
}

// ---- final: h2 = mean_agg(P) + b2 + Q, segment-max into om ----
__global__ __launch_bounds__(256) void k_final(const int* __restrict__ off,
                                               const int* __restrict__ csr,
                                               const u16* __restrict__ P,
                                               const u16* __restrict__ Q,
                                               const float* __restrict__ b2,
                                               const int* __restrict__ batch,
                                               unsigned* __restrict__ om) {
    __shared__ float sR[4][64];
    __shared__ int sG[4];
    int wv = threadIdx.x >> 6, lane = threadIdx.x & 63;
    int node = blockIdx.x * 4 + wv;  // NN % 4 == 0
    int beg = off[node], end = off[node + 1];
    float acc = 0.0f;
    for (int base = beg; base < end; base += 64) {
        int n = min(64, end - base);
        int s = (lane < n) ? csr[base + lane] : 0;
        int j = 0;
        for (; j + 3 < n; j += 4) {
            int p0 = __builtin_amdgcn_readlane(s, j) & 0x1FFFF;
            int p1 = __builtin_amdgcn_readlane(s, j + 1) & 0x1FFFF;
            int p2 = __builtin_amdgcn_readlane(s, j + 2) & 0x1FFFF;
            int p3 = __builtin_amdgcn_readlane(s, j + 3) & 0x1FFFF;
            float v0 = bf2f(P[p0 * 64 + lane]);
            float v1 = bf2f(P[p1 * 64 + lane]);
            float v2 = bf2f(P[p2 * 64 + lane]);
            float v3 = bf2f(P[p3 * 64 + lane]);
            acc += (v0 + v1) + (v2 + v3);
        }
        for (; j < n; ++j) {
            int p0 = __builtin_amdgcn_readlane(s, j) & 0x1FFFF;
            acc += bf2f(P[p0 * 64 + lane]);
        }
    }
    float r = acc / fmaxf((float)(end - beg), 1.0f) + b2[lane]
            + bf2f(Q[node * 64 + lane]);
    int g = batch[node];
    sR[wv][lane] = r;
    if (lane == 0) sG[wv] = g;
    __syncthreads();
    bool leader = (wv == 0) || (sG[wv - 1] != g);
    if (leader) {
        float m = r;
        for (int u = wv + 1; u < 4 && sG[u] == g; ++u) m = fmaxf(m, sR[u][lane]);
        atomicMax(&om[g * 64 + lane], encF(m));
    }
}

__global__ void k_decode(const unsigned* __restrict__ om, float* __restrict__ out) {
    int i = blockIdx.x * blockDim.x + threadIdx.x;
    if (i < NG * 64) out[i] = decF(om[i]);
}

extern "C" void kernel_launch(void* const* d_in, const int* in_sizes, int n_in,
                              void* d_out, int out_size, void* d_ws, size_t ws_size,
                              hipStream_t stream) {
    const int*   x     = (const int*)d_in[0];
    const int*   ei    = (const int*)d_in[1];   // [2, NE] flat: src | dst
    const int*   batch = (const int*)d_in[2];
    // d_in[3] = edge_attr, unused by SAGEConv
    const float* emb   = (const float*)d_in[4];
    const float* W1l   = (const float*)d_in[5];
    const float* b1    = (const float*)d_in[6];
    const float* W1r   = (const float*)d_in[7];
    const float* W2l   = (const float*)d_in[8];
    const float* b2    = (const float*)d_in[9];
    const float* W2r   = (const float*)d_in[10];
    float* out = (float*)d_out;

    // workspace layout (bytes)
    char* p = (char*)d_ws;
    u16* A1   = (u16*)p;               p += (size_t)NP * 128 * 2;  // [agg1 | h0]
    u16* P    = (u16*)p;               p += (size_t)NP * 64 * 2;
    u16* Q    = (u16*)p;               p += (size_t)NP * 64 * 2;
    int* csr  = (int*)p;               p += (size_t)NE * 4;
    unsigned* gbuf = (unsigned*)p;     p += (size_t)NBUK * CAP * 4;
    int* gcur = (int*)p;               p += NBUK * 4;
    int* off  = (int*)p;               p += (size_t)(NN + 1) * 4;
    u16* Wpk1 = (u16*)p;               p += 16384 * 2;
    u16* Wpk2 = (u16*)p;               p += 16384 * 2;
    u16* embB = (u16*)p;               p += (size_t)VOCAB * 64 * 2;
    unsigned* om = (unsigned*)p;

    hipMemsetAsync(gcur, 0, sizeof(int) * NBUK, stream);
    k_prep<<<2644, 256, 0, stream>>>(emb, embB, W1l, W1r, Wpk1, W2l, W2r, Wpk2, om);
    k_bucket<<<256, 256, 0, stream>>>(ei, gcur, gbuf);
    k_csr<<<NBUK, 1024, 0, stream>>>(gbuf, gcur, x, off, csr);
    k_gather1<<<(NN * 64 + 255) / 256, 256, 0, stream>>>(off, csr, x, embB, A1);
    k_gemm12<<<NP / 64, 256, 0, stream>>>(A1, Wpk1, Wpk2, b1, P, Q);
    k_final<<<NN / 4, 256, 0, stream>>>(off, csr, P, Q, b2, batch, om);
    k_decode<<<(NG * 64 + 255) / 256, 256, 0, stream>>>(om, out);
}

// Round 8
// 253.213 us; speedup vs baseline: 1.7340x; 1.1197x over previous
//
#include <hip/hip_runtime.h>
#include <cstdint>

#define NN 100000      // nodes
#define NE 1600000     // edges
#define NG 512         // graphs
#define NP 100032      // NN padded to 64*1563
#define VOCAB 10000
#define NBUK 64        // dst-range buckets
#define BSZ 1563       // nodes per bucket (64*1563 = 100032 >= NN)
#define CAP 28672      // max edges per bucket (avg 25000)
#define TILE 2048

typedef unsigned short u16;
typedef u16      u16x8  __attribute__((ext_vector_type(8)));
typedef __bf16   bf16x8 __attribute__((ext_vector_type(8)));
typedef float    f32x4  __attribute__((ext_vector_type(4)));
typedef unsigned uint4v __attribute__((ext_vector_type(4)));

__device__ __forceinline__ u16 f2bf(float f) {  // RNE
    unsigned u = __float_as_uint(f);
    unsigned r = ((u >> 16) & 1u) + 0x7FFFu;
    return (u16)((u + r) >> 16);
}
__device__ __forceinline__ float bf2f(u16 h) {
    return __uint_as_float(((unsigned)h) << 16);
}

// monotone float->uint encoding so unsigned atomicMax == float max
__device__ __forceinline__ unsigned encF(float f) {
    unsigned s = __float_as_uint(f);
    return (s & 0x80000000u) ? ~s : (s | 0x80000000u);
}
__device__ __forceinline__ float decF(unsigned m) {
    unsigned s = (m & 0x80000000u) ? (m ^ 0x80000000u) : ~m;
    return __uint_as_float(s);
}

// ---- vectorized gather core: 8 rows per load instr, 8 dims/lane ----
// acc[j] accumulates dim (lane&7)*8+j over rows with rowsub == lane>>3 (mod 8)
template <bool HI>
__device__ __forceinline__ void gather8(const int* __restrict__ csr, int beg, int end,
                                        const u16* __restrict__ table, int lane,
                                        float acc[8]) {
    const int sub = lane >> 3, g8 = (lane & 7) * 8;
    for (int base = beg; base < end; base += 64) {
        int n = min(64, end - base);
        int s = (lane < n) ? csr[base + lane] : 0;
        for (int c = 0; c * 8 < n; c += 2) {
            int i0 = c * 8 + sub;
            int e0 = __shfl(s, i0, 64);
            int r0 = HI ? (e0 >> 17) : (e0 & 0x1FFFF);
            u16x8 v0 = *(const u16x8*)(table + (size_t)r0 * 64 + g8);
            bool m1 = (c + 1) * 8 < n;
            int i1 = (c + 1) * 8 + sub;
            int e1 = __shfl(s, m1 ? i1 : 0, 64);
            int r1 = HI ? (e1 >> 17) : (e1 & 0x1FFFF);
            u16x8 v1 = *(const u16x8*)(table + (size_t)r1 * 64 + g8);
            unsigned k0 = (i0 < n) ? 0xFFFFFFFFu : 0u;
            unsigned k1 = (m1 && i1 < n) ? 0xFFFFFFFFu : 0u;
            uint4v u0 = __builtin_bit_cast(uint4v, v0);
            uint4v u1 = __builtin_bit_cast(uint4v, v1);
            #pragma unroll
            for (int k = 0; k < 4; ++k) {
                unsigned a = u0[k] & k0, b = u1[k] & k1;
                acc[2 * k]     += __uint_as_float(a << 16);
                acc[2 * k + 1] += __uint_as_float(a & 0xFFFF0000u);
                acc[2 * k]     += __uint_as_float(b << 16);
                acc[2 * k + 1] += __uint_as_float(b & 0xFFFF0000u);
            }
        }
    }
}

// per-wave LDS transpose reduce: returns total for dim = lane
__device__ __forceinline__ float reduce_dim(const float acc[8], float* sT, int lane) {
    const int sub = lane >> 3, g8 = (lane & 7) * 8;
    #pragma unroll
    for (int j = 0; j < 8; ++j) sT[sub * 64 + g8 + j] = acc[j];
    float t = 0.0f;
    #pragma unroll
    for (int sg = 0; sg < 8; ++sg) t += sT[sg * 64 + lane];
    return t;
}

// ---- fused prep: embB cast, both weight packs, outmax init ----
__device__ __forceinline__ void prepW_body(const float* __restrict__ Wa,
                                           const float* __restrict__ Wb,
                                           int mode, u16* __restrict__ Wpk, int idx) {
    int fid = idx >> 6, lane = idx & 63;
    int cT = fid >> 2, ks = fid & 3;
    int quad = lane >> 4, l16 = lane & 15;
    int n = cT * 16 + l16;
    u16x8 v;
    #pragma unroll
    for (int j = 0; j < 8; ++j) {
        int k = ks * 32 + quad * 8 + j;
        float f = (mode == 0) ? (k < 64 ? Wa[k * 128 + n] : Wb[(k - 64) * 128 + n])
                              : (n < 64 ? Wa[k * 64 + n] : Wb[k * 64 + (n - 64)]);
        v[j] = f2bf(f);
    }
    *(u16x8*)(Wpk + idx * 8) = v;
}

__global__ __launch_bounds__(256) void k_prep(
        const float* __restrict__ emb, u16* __restrict__ embB,
        const float* __restrict__ W1l, const float* __restrict__ W1r,
        u16* __restrict__ Wpk1,
        const float* __restrict__ W2l, const float* __restrict__ W2r,
        u16* __restrict__ Wpk2, unsigned* __restrict__ om) {
    int bid = blockIdx.x, t = threadIdx.x;
    if (bid < 2500) {
        int i = bid * 256 + t;
        if (i < VOCAB * 64) embB[i] = f2bf(emb[i]);
    } else if (bid < 2508) {
        prepW_body(W1l, W1r, 0, Wpk1, (bid - 2500) * 256 + t);
    } else if (bid < 2516) {
        prepW_body(W2l, W2r, 1, Wpk2, (bid - 2508) * 256 + t);
    } else {
        int i = (bid - 2516) * 256 + t;
        if (i < NG * 64) om[i] = 0x007FFFFFu;  // encF(-inf)
    }
}

// ---- pass 1: partition edges into 64 dst-range buckets (LDS counting sort/tile) ----
// entry = dstlocal(11) | src(17)
__global__ __launch_bounds__(256) void k_bucket(const int* __restrict__ ei,
                                                int* __restrict__ gcur,
                                                unsigned* __restrict__ gbuf) {
    __shared__ int cnt[NBUK];
    __shared__ int start[NBUK];
    __shared__ int gbase[NBUK];
    __shared__ unsigned buf[TILE];
    __shared__ unsigned char bkt[TILE];
    const int t = threadIdx.x;
    const int e0 = blockIdx.x * (NE / 256);   // 6250 edges per block
    const int e1 = e0 + (NE / 256);
    for (int tb = e0; tb < e1; tb += TILE) {
        const int tc = min(TILE, e1 - tb);
        if (t < NBUK) cnt[t] = 0;
        __syncthreads();
        // phase A: load + rank within tile
        unsigned ent[TILE / 256];
        unsigned char eb[TILE / 256];
        u16 rk[TILE / 256];
        int nm = 0;
        for (int i = t; i < tc; i += 256) {
            int dst = ei[NE + tb + i];
            int src = ei[tb + i];
            unsigned b = (unsigned)dst / BSZ;
            unsigned dl = (unsigned)dst - b * BSZ;
            ent[nm] = (dl << 17) | (unsigned)src;
            eb[nm] = (unsigned char)b;
            rk[nm] = (u16)atomicAdd(&cnt[b], 1);
            ++nm;
        }
        __syncthreads();
        // phase B: wave-0 shuffle scan of 64 counts + global reservation
        if (t < 64) {
            int c = cnt[t];
            int s = c;
            #pragma unroll
            for (int d = 1; d < 64; d <<= 1) {
                int v = __shfl_up(s, d, 64);
                if (t >= d) s += v;
            }
            start[t] = s - c;
            gbase[t] = atomicAdd(&gcur[t], c);
        }
        __syncthreads();
        // phase C: place into bucket-sorted LDS buffer
        for (int k = 0; k < nm; ++k) {
            int pos = start[eb[k]] + rk[k];
            buf[pos] = ent[k];
            bkt[pos] = eb[k];
        }
        __syncthreads();
        // phase D: coalesced flush
        for (int i = t; i < tc; i += 256) {
            unsigned b = bkt[i];
            gbuf[(size_t)b * CAP + gbase[b] + (i - start[b])] = buf[i];
        }
        __syncthreads();
    }
}

// ---- pass 2: per-bucket histogram -> scan -> offsets -> fill csr (one block/bucket) ----
// csr entry = src | (x[src] << 17)
__global__ __launch_bounds__(1024) void k_csr(const unsigned* __restrict__ gbuf,
                                              const int* __restrict__ gcur,
                                              const int* __restrict__ x,
                                              int* __restrict__ off,
                                              int* __restrict__ csr) {
    __shared__ int hist[BSZ];
    __shared__ int curL[BSZ];
    __shared__ int sc[1024];
    __shared__ int sb[64];
    const int b = blockIdx.x, t = threadIdx.x;
    for (int i = t; i < BSZ; i += 1024) hist[i] = 0;
    // bucket global base = sum gcur[0..b)
    if (t < 64) sb[t] = (t < b) ? gcur[t] : 0;
    __syncthreads();
    const int size = gcur[b];
    const unsigned* gb = gbuf + (size_t)b * CAP;
    for (int i = t; i < size; i += 1024)
        atomicAdd(&hist[gb[i] >> 17], 1);
    for (int d = 32; d > 0; d >>= 1) {
        if (t < d) sb[t] += sb[t + d];
        __syncthreads();
    }
    const int gbase = sb[0];
    // exclusive scan of hist[0..BSZ): thread t owns elements 2t, 2t+1
    int a0 = (2 * t < BSZ) ? hist[2 * t] : 0;
    int a1 = (2 * t + 1 < BSZ) ? hist[2 * t + 1] : 0;
    sc[t] = a0 + a1;
    __syncthreads();
    for (int d = 1; d < 1024; d <<= 1) {
        int v = (t >= d) ? sc[t - d] : 0;
        __syncthreads();
        sc[t] += v;
        __syncthreads();
    }
    int ex = (t == 0) ? 0 : sc[t - 1];
    if (2 * t < BSZ) hist[2 * t] = ex;
    if (2 * t + 1 < BSZ) hist[2 * t + 1] = ex + a0;
    __syncthreads();
    const int g0 = b * BSZ;
    for (int i = t; i < BSZ; i += 1024) {
        int v = gbase + hist[i];
        curL[i] = v;
        if (g0 + i <= NN) off[g0 + i] = v;  // bucket 63 writes off[NN]=NE
    }
    __syncthreads();
    for (int i = t; i < size; i += 1024) {
        unsigned ent = gb[i];
        int src = (int)(ent & 0x1FFFFu);
        int dl  = (int)(ent >> 17);
        int pos = atomicAdd(&curL[dl], 1);
        csr[pos] = src | (x[src] << 17);
    }
}

// ---- gather-mean of emb[x[src]] into cols 0..63 of A1; own emb into 64..127 ----
__global__ __launch_bounds__(256) void k_gather1(const int* __restrict__ off,
                                                 const int* __restrict__ csr,
                                                 const int* __restrict__ x,
                                                 const u16* __restrict__ embB,
                                                 u16* __restrict__ A1) {
    __shared__ float sT[4][512];
    int wv = threadIdx.x >> 6, lane = threadIdx.x & 63;
    for (int grp = blockIdx.x; grp * 4 < NN; grp += gridDim.x) {
        int wid = grp * 4 + wv;  // NN % 4 == 0
        int beg = off[wid], end = off[wid + 1];
        float acc[8] = {0.f, 0.f, 0.f, 0.f, 0.f, 0.f, 0.f, 0.f};
        gather8<true>(csr, beg, end, embB, lane, acc);
        float t = reduce_dim(acc, sT[wv], lane);
        A1[wid * 128 + lane] = f2bf(t / fmaxf((float)(end - beg), 1.0f));
        A1[wid * 128 + 64 + lane] = embB[x[wid] * 64 + lane];  // fused embed
    }
}

// ---- fused GEMM1+GEMM2 through LDS: H1 = relu(A1@W1+b1); [P|Q] = H1@W2 ----
__global__ __launch_bounds__(256) void k_gemm12(
        const u16* __restrict__ A1, const u16* __restrict__ Wpk1,
        const u16* __restrict__ Wpk2, const float* __restrict__ b1,
        u16* __restrict__ P, u16* __restrict__ Q) {
    __shared__ __align__(16) u16 sH1[64][136];  // pad: 272 B row stride
    int w = threadIdx.x >> 6, lane = threadIdx.x & 63;
    int quad = lane >> 4, l16 = lane & 15;
    u16x8 bf1[2][4], bf2[2][4];
    #pragma unroll
    for (int ct = 0; ct < 2; ++ct)
        #pragma unroll
        for (int ks = 0; ks < 4; ++ks) {
            int fid = (w * 2 + ct) * 4 + ks;
            bf1[ct][ks] = *(const u16x8*)(Wpk1 + (fid * 64 + lane) * 8);
            bf2[ct][ks] = *(const u16x8*)(Wpk2 + (fid * 64 + lane) * 8);
        }
    int r0 = blockIdx.x * 64;
    // stage 1: H1 tile -> LDS
    #pragma unroll
    for (int rt = 0; rt < 4; ++rt) {
        int row = r0 + rt * 16 + l16;
        u16x8 a[4];
        #pragma unroll
        for (int ks = 0; ks < 4; ++ks)
            a[ks] = *(const u16x8*)(A1 + row * 128 + ks * 32 + quad * 8);
        #pragma unroll
        for (int ct = 0; ct < 2; ++ct) {
            f32x4 acc = {0.f, 0.f, 0.f, 0.f};
            #pragma unroll
            for (int ks = 0; ks < 4; ++ks)
                acc = __builtin_amdgcn_mfma_f32_16x16x32_bf16(
                    __builtin_bit_cast(bf16x8, a[ks]),
                    __builtin_bit_cast(bf16x8, bf1[ct][ks]), acc, 0, 0, 0);
            int col = w * 32 + ct * 16 + l16;
            float bias = b1[col];
            int lr = rt * 16 + quad * 4;
            #pragma unroll
            for (int reg = 0; reg < 4; ++reg)
                sH1[lr + reg][col] = f2bf(fmaxf(acc[reg] + bias, 0.f));
        }
    }
    __syncthreads();
    // stage 2: [P|Q] from LDS H1
    #pragma unroll
    for (int rt = 0; rt < 4; ++rt) {
        u16x8 a[4];
        #pragma unroll
        for (int ks = 0; ks < 4; ++ks)
            a[ks] = *(const u16x8*)(&sH1[rt * 16 + l16][ks * 32 + quad * 8]);
        #pragma unroll
        for (int ct = 0; ct < 2; ++ct) {
            f32x4 acc = {0.f, 0.f, 0.f, 0.f};
            #pragma unroll
            for (int ks = 0; ks < 4; ++ks)
                acc = __builtin_amdgcn_mfma_f32_16x16x32_bf16(
                    __builtin_bit_cast(bf16x8, a[ks]),
                    __builtin_bit_cast(bf16x8, bf2[ct][ks]), acc, 0, 0, 0);
            int col = w * 32 + ct * 16 + l16;
            int gr = r0 + rt * 16 + quad * 4;
            u16* dstT = (col < 64) ? P : Q;
            int c = col & 63;
            #pragma unroll
            for (int reg = 0; reg < 4; ++reg)
                dstT[(gr + reg) * 64 + c] = f2bf(acc[reg]);
        }
    }
}

// ---- final: h2 = mean_agg(P) + b2 + Q, segment-max into om ----
__global__ __launch_bounds__(256) void k_final(const int* __restrict__ off,
                                               const int* __restrict__ csr,
                                               const u16* __restrict__ P,
                                               const u16* __restrict__ Q,
                                               const float* __restrict__ b2,
                                               const int* __restrict__ batch,
                                               unsigned* __restrict__ om) {
    __shared__ float sT[4][512];
    __shared__ float sR[4][64];
    __shared__ int sG[4];
    int wv = threadIdx.x >> 6, lane = threadIdx.x & 63;
    for (int grp = blockIdx.x; grp * 4 < NN; grp += gridDim.x) {
        int node = grp * 4 + wv;  // NN % 4 == 0
        int beg = off[node], end = off[node + 1];
        float acc[8] = {0.f, 0.f, 0.f, 0.f, 0.f, 0.f, 0.f, 0.f};
        gather8<false>(csr, beg, end, P, lane, acc);
        float t = reduce_dim(acc, sT[wv], lane);
        float r = t / fmaxf((float)(end - beg), 1.0f) + b2[lane]
                + bf2f(Q[node * 64 + lane]);
        int g = batch[node];
        sR[wv][lane] = r;
        if (lane == 0) sG[wv] = g;
        __syncthreads();
        bool leader = (wv == 0) || (sG[wv - 1] != g);
        if (leader) {
            float m = r;
            for (int u = wv + 1; u < 4 && sG[u] == g; ++u) m = fmaxf(m, sR[u][lane]);
            atomicMax(&om[g * 64 + lane], encF(m));
        }
        __syncthreads();
    }
}

__global__ void k_decode(const unsigned* __restrict__ om, float* __restrict__ out) {
    int i = blockIdx.x * blockDim.x + threadIdx.x;
    if (i < NG * 64) out[i] = decF(om[i]);
}

extern "C" void kernel_launch(void* const* d_in, const int* in_sizes, int n_in,
                              void* d_out, int out_size, void* d_ws, size_t ws_size,
                              hipStream_t stream) {
    const int*   x     = (const int*)d_in[0];
    const int*   ei    = (const int*)d_in[1];   // [2, NE] flat: src | dst
    const int*   batch = (const int*)d_in[2];
    // d_in[3] = edge_attr, unused by SAGEConv
    const float* emb   = (const float*)d_in[4];
    const float* W1l   = (const float*)d_in[5];
    const float* b1    = (const float*)d_in[6];
    const float* W1r   = (const float*)d_in[7];
    const float* W2l   = (const float*)d_in[8];
    const float* b2    = (const float*)d_in[9];
    const float* W2r   = (const float*)d_in[10];
    float* out = (float*)d_out;

    // workspace layout (bytes)
    char* p = (char*)d_ws;
    u16* A1   = (u16*)p;               p += (size_t)NP * 128 * 2;  // [agg1 | h0]
    u16* P    = (u16*)p;               p += (size_t)NP * 64 * 2;
    u16* Q    = (u16*)p;               p += (size_t)NP * 64 * 2;
    int* csr  = (int*)p;               p += (size_t)NE * 4;
    unsigned* gbuf = (unsigned*)p;     p += (size_t)NBUK * CAP * 4;
    int* gcur = (int*)p;               p += NBUK * 4;
    int* off  = (int*)p;               p += (size_t)(NN + 1) * 4;
    u16* Wpk1 = (u16*)p;               p += 16384 * 2;
    u16* Wpk2 = (u16*)p;               p += 16384 * 2;
    u16* embB = (u16*)p;               p += (size_t)VOCAB * 64 * 2;
    unsigned* om = (unsigned*)p;

    hipMemsetAsync(gcur, 0, sizeof(int) * NBUK, stream);
    k_prep<<<2644, 256, 0, stream>>>(emb, embB, W1l, W1r, Wpk1, W2l, W2r, Wpk2, om);
    k_bucket<<<256, 256, 0, stream>>>(ei, gcur, gbuf);
    k_csr<<<NBUK, 1024, 0, stream>>>(gbuf, gcur, x, off, csr);
    k_gather1<<<2048, 256, 0, stream>>>(off, csr, x, embB, A1);
    k_gemm12<<<NP / 64, 256, 0, stream>>>(A1, Wpk1, Wpk2, b1, P, Q);
    k_final<<<2048, 256, 0, stream>>>(off, csr, P, Q, b2, batch, om);
    k_decode<<<(NG * 64 + 255) / 256, 256, 0, stream>>>(om, out);
}

// Round 9
// 226.711 us; speedup vs baseline: 1.9367x; 1.1169x over previous
//
#include <hip/hip_runtime.h>
#include <cstdint>

#define NN 100000      // nodes
#define NE 1600000     // edges
#define NG 512         // graphs
#define NP 100032      // NN padded to 64*1563
#define VOCAB 10000
#define NBUK 256       // dst-range buckets
#define BSZ 391        // nodes per bucket (256*391 = 100096 >= NN+1)
#define CAP 7680       // max edges per bucket (avg 6250, +18 sigma)
#define TILE 2048

typedef unsigned short u16;
typedef u16      u16x8  __attribute__((ext_vector_type(8)));
typedef __bf16   bf16x8 __attribute__((ext_vector_type(8)));
typedef float    f32x4  __attribute__((ext_vector_type(4)));
typedef unsigned uint4v __attribute__((ext_vector_type(4)));

__device__ __forceinline__ u16 f2bf(float f) {  // RNE
    unsigned u = __float_as_uint(f);
    unsigned r = ((u >> 16) & 1u) + 0x7FFFu;
    return (u16)((u + r) >> 16);
}
__device__ __forceinline__ float bf2f(u16 h) {
    return __uint_as_float(((unsigned)h) << 16);
}

// monotone float->uint encoding so unsigned atomicMax == float max
__device__ __forceinline__ unsigned encF(float f) {
    unsigned s = __float_as_uint(f);
    return (s & 0x80000000u) ? ~s : (s | 0x80000000u);
}
__device__ __forceinline__ float decF(unsigned m) {
    unsigned s = (m & 0x80000000u) ? (m ^ 0x80000000u) : ~m;
    return __uint_as_float(s);
}

// ---- vectorized gather core: 8 rows per load instr, 8 dims/lane, 4 chunks in flight ----
template <bool HI>
__device__ __forceinline__ void gather8(const int* __restrict__ csr, int beg, int end,
                                        const u16* __restrict__ table, int lane,
                                        float acc[8]) {
    const int sub = lane >> 3, g8 = (lane & 7) * 8;
    for (int base = beg; base < end; base += 64) {
        int n = min(64, end - base);
        int s = (lane < n) ? csr[base + lane] : 0;
        for (int c = 0; c * 8 < n; c += 4) {
            u16x8 vv[4];
            unsigned kk[4];
            #pragma unroll
            for (int u = 0; u < 4; ++u) {
                int i = (c + u) * 8 + sub;
                bool act = (c + u) * 8 < n;
                int e = __shfl(s, act ? i : 0, 64);
                int r = HI ? (e >> 17) : (e & 0x1FFFF);
                vv[u] = *(const u16x8*)(table + (size_t)r * 64 + g8);
                kk[u] = (act && i < n) ? 0xFFFFFFFFu : 0u;
            }
            #pragma unroll
            for (int u = 0; u < 4; ++u) {
                uint4v uv = __builtin_bit_cast(uint4v, vv[u]);
                #pragma unroll
                for (int k = 0; k < 4; ++k) {
                    unsigned a = uv[k] & kk[u];
                    acc[2 * k]     += __uint_as_float(a << 16);
                    acc[2 * k + 1] += __uint_as_float(a & 0xFFFF0000u);
                }
            }
        }
    }
}

// per-wave LDS transpose reduce: returns total for dim = lane
__device__ __forceinline__ float reduce_dim(const float acc[8], float* sT, int lane) {
    const int sub = lane >> 3, g8 = (lane & 7) * 8;
    #pragma unroll
    for (int j = 0; j < 8; ++j) sT[sub * 64 + g8 + j] = acc[j];
    float t = 0.0f;
    #pragma unroll
    for (int sg = 0; sg < 8; ++sg) t += sT[sg * 64 + lane];
    return t;
}

// ---- fused prep: embB cast, both weight packs, outmax init ----
__device__ __forceinline__ void prepW_body(const float* __restrict__ Wa,
                                           const float* __restrict__ Wb,
                                           int mode, u16* __restrict__ Wpk, int idx) {
    int fid = idx >> 6, lane = idx & 63;
    int cT = fid >> 2, ks = fid & 3;
    int quad = lane >> 4, l16 = lane & 15;
    int n = cT * 16 + l16;
    u16x8 v;
    #pragma unroll
    for (int j = 0; j < 8; ++j) {
        int k = ks * 32 + quad * 8 + j;
        float f = (mode == 0) ? (k < 64 ? Wa[k * 128 + n] : Wb[(k - 64) * 128 + n])
                              : (n < 64 ? Wa[k * 64 + n] : Wb[k * 64 + (n - 64)]);
        v[j] = f2bf(f);
    }
    *(u16x8*)(Wpk + idx * 8) = v;
}

__global__ __launch_bounds__(256) void k_prep(
        const float* __restrict__ emb, u16* __restrict__ embB,
        const float* __restrict__ W1l, const float* __restrict__ W1r,
        u16* __restrict__ Wpk1,
        const float* __restrict__ W2l, const float* __restrict__ W2r,
        u16* __restrict__ Wpk2, unsigned* __restrict__ om) {
    int bid = blockIdx.x, t = threadIdx.x;
    if (bid < 2500) {
        int i = bid * 256 + t;
        if (i < VOCAB * 64) embB[i] = f2bf(emb[i]);
    } else if (bid < 2508) {
        prepW_body(W1l, W1r, 0, Wpk1, (bid - 2500) * 256 + t);
    } else if (bid < 2516) {
        prepW_body(W2l, W2r, 1, Wpk2, (bid - 2508) * 256 + t);
    } else {
        int i = (bid - 2516) * 256 + t;
        if (i < NG * 64) om[i] = 0x007FFFFFu;  // encF(-inf)
    }
}

// ---- pass 1: partition edges into 256 dst-range buckets (LDS counting sort/tile) ----
// entry = dstlocal(9) | src(17)
__global__ __launch_bounds__(256) void k_bucket(const int* __restrict__ ei,
                                                int* __restrict__ gcur,
                                                unsigned* __restrict__ gbuf) {
    __shared__ int cnt[NBUK];
    __shared__ int start[NBUK];
    __shared__ int gbase[NBUK];
    __shared__ int wsum[4];
    __shared__ unsigned buf[TILE];
    __shared__ unsigned char bkt[TILE];
    const int t = threadIdx.x;
    const int e0 = blockIdx.x * (NE / 256);   // 6250 edges per block
    const int e1 = e0 + (NE / 256);
    for (int tb = e0; tb < e1; tb += TILE) {
        const int tc = min(TILE, e1 - tb);
        cnt[t] = 0;
        __syncthreads();
        // phase A: load + rank within tile
        unsigned ent[TILE / 256];
        unsigned char eb[TILE / 256];
        u16 rk[TILE / 256];
        int nm = 0;
        for (int i = t; i < tc; i += 256) {
            int dst = ei[NE + tb + i];
            int src = ei[tb + i];
            unsigned b = (unsigned)dst / BSZ;
            unsigned dl = (unsigned)dst - b * BSZ;
            ent[nm] = (dl << 17) | (unsigned)src;
            eb[nm] = (unsigned char)b;
            rk[nm] = (u16)atomicAdd(&cnt[b], 1);
            ++nm;
        }
        __syncthreads();
        // phase B: 4-wave shuffle scan of 256 counts + global reservation
        {
            int c = cnt[t];
            int s = c;
            #pragma unroll
            for (int d = 1; d < 64; d <<= 1) {
                int v = __shfl_up(s, d, 64);
                if ((t & 63) >= d) s += v;
            }
            if ((t & 63) == 63) wsum[t >> 6] = s;
            __syncthreads();
            int pre = 0;
            #pragma unroll
            for (int w = 0; w < 4; ++w) pre += (w < (t >> 6)) ? wsum[w] : 0;
            start[t] = pre + s - c;
            gbase[t] = atomicAdd(&gcur[t], c);
        }
        __syncthreads();
        // phase C: place into bucket-sorted LDS buffer
        for (int k = 0; k < nm; ++k) {
            int pos = start[eb[k]] + rk[k];
            buf[pos] = ent[k];
            bkt[pos] = eb[k];
        }
        __syncthreads();
        // phase D: coalesced flush
        for (int i = t; i < tc; i += 256) {
            unsigned b = bkt[i];
            gbuf[(size_t)b * CAP + gbase[b] + (i - start[b])] = buf[i];
        }
        __syncthreads();
    }
}

// ---- pass 2: per-bucket histogram -> wave scan -> offsets -> fill (1 block/bucket) ----
// csr entry = src | (x[src] << 17)
__global__ __launch_bounds__(512) void k_csr(const unsigned* __restrict__ gbuf,
                                             const int* __restrict__ gcur,
                                             const int* __restrict__ x,
                                             int* __restrict__ off,
                                             int* __restrict__ csr) {
    __shared__ int hist[BSZ];
    __shared__ int curL[BSZ];
    __shared__ int wsum[8];
    __shared__ int sred[8];
    const int b = blockIdx.x, t = threadIdx.x;
    if (t < BSZ) hist[t] = 0;
    __syncthreads();
    const int size = gcur[b];
    const unsigned* gb = gbuf + (size_t)b * CAP;
    for (int i = t; i < size; i += 512)
        atomicAdd(&hist[gb[i] >> 17], 1);
    // bucket global base = sum gcur[0..b) (independent of hist)
    {
        int v = (t < 256 && t < b) ? gcur[t] : 0;
        #pragma unroll
        for (int d = 32; d > 0; d >>= 1) v += __shfl_down(v, d, 64);
        if ((t & 63) == 0) sred[t >> 6] = v;
    }
    __syncthreads();
    const int gbase = sred[0] + sred[1] + sred[2] + sred[3];
    // single-pass shuffle scan over hist[0..BSZ)
    int h = (t < BSZ) ? hist[t] : 0;
    int s = h;
    #pragma unroll
    for (int d = 1; d < 64; d <<= 1) {
        int v = __shfl_up(s, d, 64);
        if ((t & 63) >= d) s += v;
    }
    if ((t & 63) == 63) wsum[t >> 6] = s;
    __syncthreads();
    int pre = 0;
    #pragma unroll
    for (int w = 0; w < 7; ++w) pre += (w < (t >> 6)) ? wsum[w] : 0;
    if (t < BSZ) {
        int ex = gbase + pre + s - h;  // exclusive global offset
        curL[t] = ex;
        int g0 = b * BSZ;
        if (g0 + t <= NN) off[g0 + t] = ex;  // covers off[NN]=NE (b=255,t=295)
    }
    __syncthreads();
    for (int i = t; i < size; i += 512) {
        unsigned ent = gb[i];
        int src = (int)(ent & 0x1FFFFu);
        int dl  = (int)(ent >> 17);
        int pos = atomicAdd(&curL[dl], 1);
        csr[pos] = src | (x[src] << 17);
    }
}

// ---- gather-mean of emb[x[src]] into cols 0..63 of A1; own emb into 64..127 ----
__global__ __launch_bounds__(256) void k_gather1(const int* __restrict__ off,
                                                 const int* __restrict__ csr,
                                                 const int* __restrict__ x,
                                                 const u16* __restrict__ embB,
                                                 u16* __restrict__ A1) {
    __shared__ float sT[4][512];
    int wv = threadIdx.x >> 6, lane = threadIdx.x & 63;
    for (int grp = blockIdx.x; grp * 4 < NN; grp += gridDim.x) {
        int wid = grp * 4 + wv;  // NN % 4 == 0
        int beg = off[wid], end = off[wid + 1];
        float acc[8] = {0.f, 0.f, 0.f, 0.f, 0.f, 0.f, 0.f, 0.f};
        gather8<true>(csr, beg, end, embB, lane, acc);
        float t = reduce_dim(acc, sT[wv], lane);
        A1[wid * 128 + lane] = f2bf(t / fmaxf((float)(end - beg), 1.0f));
        A1[wid * 128 + 64 + lane] = embB[x[wid] * 64 + lane];  // fused embed
    }
}

// ---- fused GEMM1+GEMM2 through LDS: H1 = relu(A1@W1+b1); [P|Q] = H1@W2 ----
__global__ __launch_bounds__(256) void k_gemm12(
        const u16* __restrict__ A1, const u16* __restrict__ Wpk1,
        const u16* __restrict__ Wpk2, const float* __restrict__ b1,
        u16* __restrict__ P, u16* __restrict__ Q) {
    __shared__ __align__(16) u16 sH1[64][136];  // pad: 272 B row stride
    int w = threadIdx.x >> 6, lane = threadIdx.x & 63;
    int quad = lane >> 4, l16 = lane & 15;
    u16x8 bf1[2][4], bf2[2][4];
    #pragma unroll
    for (int ct = 0; ct < 2; ++ct)
        #pragma unroll
        for (int ks = 0; ks < 4; ++ks) {
            int fid = (w * 2 + ct) * 4 + ks;
            bf1[ct][ks] = *(const u16x8*)(Wpk1 + (fid * 64 + lane) * 8);
            bf2[ct][ks] = *(const u16x8*)(Wpk2 + (fid * 64 + lane) * 8);
        }
    int r0 = blockIdx.x * 64;
    // stage 1: H1 tile -> LDS
    #pragma unroll
    for (int rt = 0; rt < 4; ++rt) {
        int row = r0 + rt * 16 + l16;
        u16x8 a[4];
        #pragma unroll
        for (int ks = 0; ks < 4; ++ks)
            a[ks] = *(const u16x8*)(A1 + row * 128 + ks * 32 + quad * 8);
        #pragma unroll
        for (int ct = 0; ct < 2; ++ct) {
            f32x4 acc = {0.f, 0.f, 0.f, 0.f};
            #pragma unroll
            for (int ks = 0; ks < 4; ++ks)
                acc = __builtin_amdgcn_mfma_f32_16x16x32_bf16(
                    __builtin_bit_cast(bf16x8, a[ks]),
                    __builtin_bit_cast(bf16x8, bf1[ct][ks]), acc, 0, 0, 0);
            int col = w * 32 + ct * 16 + l16;
            float bias = b1[col];
            int lr = rt * 16 + quad * 4;
            #pragma unroll
            for (int reg = 0; reg < 4; ++reg)
                sH1[lr + reg][col] = f2bf(fmaxf(acc[reg] + bias, 0.f));
        }
    }
    __syncthreads();
    // stage 2: [P|Q] from LDS H1
    #pragma unroll
    for (int rt = 0; rt < 4; ++rt) {
        u16x8 a[4];
        #pragma unroll
        for (int ks = 0; ks < 4; ++ks)
            a[ks] = *(const u16x8*)(&sH1[rt * 16 + l16][ks * 32 + quad * 8]);
        #pragma unroll
        for (int ct = 0; ct < 2; ++ct) {
            f32x4 acc = {0.f, 0.f, 0.f, 0.f};
            #pragma unroll
            for (int ks = 0; ks < 4; ++ks)
                acc = __builtin_amdgcn_mfma_f32_16x16x32_bf16(
                    __builtin_bit_cast(bf16x8, a[ks]),
                    __builtin_bit_cast(bf16x8, bf2[ct][ks]), acc, 0, 0, 0);
            int col = w * 32 + ct * 16 + l16;
            int gr = r0 + rt * 16 + quad * 4;
            u16* dstT = (col < 64) ? P : Q;
            int c = col & 63;
            #pragma unroll
            for (int reg = 0; reg < 4; ++reg)
                dstT[(gr + reg) * 64 + c] = f2bf(acc[reg]);
        }
    }
}

// ---- final: h2 = mean_agg(P) + b2 + Q, segment-max into om ----
__global__ __launch_bounds__(256) void k_final(const int* __restrict__ off,
                                               const int* __restrict__ csr,
                                               const u16* __restrict__ P,
                                               const u16* __restrict__ Q,
                                               const float* __restrict__ b2,
                                               const int* __restrict__ batch,
                                               unsigned* __restrict__ om) {
    __shared__ float sT[4][512];
    __shared__ float sR[4][64];
    __shared__ int sG[4];
    int wv = threadIdx.x >> 6, lane = threadIdx.x & 63;
    for (int grp = blockIdx.x; grp * 4 < NN; grp += gridDim.x) {
        int node = grp * 4 + wv;  // NN % 4 == 0
        int beg = off[node], end = off[node + 1];
        float acc[8] = {0.f, 0.f, 0.f, 0.f, 0.f, 0.f, 0.f, 0.f};
        gather8<false>(csr, beg, end, P, lane, acc);
        float t = reduce_dim(acc, sT[wv], lane);
        float r = t / fmaxf((float)(end - beg), 1.0f) + b2[lane]
                + bf2f(Q[node * 64 + lane]);
        int g = batch[node];
        sR[wv][lane] = r;
        if (lane == 0) sG[wv] = g;
        __syncthreads();
        bool leader = (wv == 0) || (sG[wv - 1] != g);
        if (leader) {
            float m = r;
            for (int u = wv + 1; u < 4 && sG[u] == g; ++u) m = fmaxf(m, sR[u][lane]);
            atomicMax(&om[g * 64 + lane], encF(m));
        }
        __syncthreads();
    }
}

__global__ void k_decode(const unsigned* __restrict__ om, float* __restrict__ out) {
    int i = blockIdx.x * blockDim.x + threadIdx.x;
    if (i < NG * 64) out[i] = decF(om[i]);
}

extern "C" void kernel_launch(void* const* d_in, const int* in_sizes, int n_in,
                              void* d_out, int out_size, void* d_ws, size_t ws_size,
                              hipStream_t stream) {
    const int*   x     = (const int*)d_in[0];
    const int*   ei    = (const int*)d_in[1];   // [2, NE] flat: src | dst
    const int*   batch = (const int*)d_in[2];
    // d_in[3] = edge_attr, unused by SAGEConv
    const float* emb   = (const float*)d_in[4];
    const float* W1l   = (const float*)d_in[5];
    const float* b1    = (const float*)d_in[6];
    const float* W1r   = (const float*)d_in[7];
    const float* W2l   = (const float*)d_in[8];
    const float* b2    = (const float*)d_in[9];
    const float* W2r   = (const float*)d_in[10];
    float* out = (float*)d_out;

    // workspace layout (bytes)
    char* p = (char*)d_ws;
    u16* A1   = (u16*)p;               p += (size_t)NP * 128 * 2;  // [agg1 | h0]
    u16* P    = (u16*)p;               p += (size_t)NP * 64 * 2;
    u16* Q    = (u16*)p;               p += (size_t)NP * 64 * 2;
    int* csr  = (int*)p;               p += (size_t)NE * 4;
    unsigned* gbuf = (unsigned*)p;     p += (size_t)NBUK * CAP * 4;
    int* gcur = (int*)p;               p += NBUK * 4;
    int* off  = (int*)p;               p += (size_t)(NN + 1) * 4;
    u16* Wpk1 = (u16*)p;               p += 16384 * 2;
    u16* Wpk2 = (u16*)p;               p += 16384 * 2;
    u16* embB = (u16*)p;               p += (size_t)VOCAB * 64 * 2;
    unsigned* om = (unsigned*)p;

    hipMemsetAsync(gcur, 0, sizeof(int) * NBUK, stream);
    k_prep<<<2644, 256, 0, stream>>>(emb, embB, W1l, W1r, Wpk1, W2l, W2r, Wpk2, om);
    k_bucket<<<256, 256, 0, stream>>>(ei, gcur, gbuf);
    k_csr<<<NBUK, 512, 0, stream>>>(gbuf, gcur, x, off, csr);
    k_gather1<<<2048, 256, 0, stream>>>(off, csr, x, embB, A1);
    k_gemm12<<<NP / 64, 256, 0, stream>>>(A1, Wpk1, Wpk2, b1, P, Q);
    k_final<<<2048, 256, 0, stream>>>(off, csr, P, Q, b2, batch, om);
    k_decode<<<(NG * 64 + 255) / 256, 256, 0, stream>>>(om, out);
}

// Round 10
// 221.606 us; speedup vs baseline: 1.9813x; 1.0230x over previous
//
#include <hip/hip_runtime.h>
#include <cstdint>

#define NN 100000      // nodes
#define NE 1600000     // edges
#define NG 512         // graphs
#define NP 100032      // NN padded to 64*1563
#define VOCAB 10000
#define NBUK 256       // dst-range buckets
#define BSZ 391        // nodes per bucket (256*391 = 100096 >= NN+1)
#define CAP 7680       // max edges per bucket (avg 6250, +18 sigma)
#define TILE 2048

typedef unsigned short u16;
typedef u16      u16x8  __attribute__((ext_vector_type(8)));
typedef __bf16   bf16x8 __attribute__((ext_vector_type(8)));
typedef float    f32x4  __attribute__((ext_vector_type(4)));
typedef float    f32x2  __attribute__((ext_vector_type(2)));
typedef unsigned uint4v __attribute__((ext_vector_type(4)));

__device__ __forceinline__ u16 f2bf(float f) {  // RNE
    unsigned u = __float_as_uint(f);
    unsigned r = ((u >> 16) & 1u) + 0x7FFFu;
    return (u16)((u + r) >> 16);
}
__device__ __forceinline__ float bf2f(u16 h) {
    return __uint_as_float(((unsigned)h) << 16);
}

// monotone float->uint encoding so unsigned atomicMax == float max
__device__ __forceinline__ unsigned encF(float f) {
    unsigned s = __float_as_uint(f);
    return (s & 0x80000000u) ? ~s : (s | 0x80000000u);
}
__device__ __forceinline__ float decF(unsigned m) {
    unsigned s = (m & 0x80000000u) ? (m ^ 0x80000000u) : ~m;
    return __uint_as_float(s);
}

// ---- vectorized gather core: 8 rows per load instr, 8 dims/lane ----
// acc[k] accumulates dims (lane&7)*8 + {2k, 2k+1}; rows with rowsub == lane>>3
template <bool HI>
__device__ __forceinline__ void gather8(const int* __restrict__ csr, int beg, int end,
                                        const u16* __restrict__ table, int lane,
                                        f32x2 acc[4]) {
    const int sub = lane >> 3, g8 = (lane & 7) * 8;
    for (int base = beg; base < end; base += 64) {
        int n = min(64, end - base);
        int s = (lane < n) ? csr[base + lane] : 0;
        for (int c = 0; c * 8 < n; c += 2) {
            #pragma unroll
            for (int u = 0; u < 2; ++u) {
                int i = (c + u) * 8 + sub;        // max 63 since n<=64
                int e = __shfl(s, i, 64);          // all lanes participate
                u16x8 v = {0, 0, 0, 0, 0, 0, 0, 0};
                if (i < n) {
                    int r = HI ? (e >> 17) : (e & 0x1FFFF);
                    v = *(const u16x8*)(table + (size_t)r * 64 + g8);
                }
                uint4v uv = __builtin_bit_cast(uint4v, v);
                #pragma unroll
                for (int k = 0; k < 4; ++k) {
                    f32x2 w;
                    w[0] = __uint_as_float(uv[k] << 16);
                    w[1] = __uint_as_float(uv[k] & 0xFFFF0000u);
                    acc[k] += w;                   // v_pk_add_f32
                }
            }
        }
    }
}

// per-wave LDS transpose reduce (stride 72 breaks the 8-way bank conflict)
__device__ __forceinline__ float reduce_dim(const f32x2 acc[4], float* sT, int lane) {
    const int sub = lane >> 3, g8 = (lane & 7) * 8;
    #pragma unroll
    for (int k = 0; k < 4; ++k) {
        sT[sub * 72 + g8 + 2 * k]     = acc[k][0];
        sT[sub * 72 + g8 + 2 * k + 1] = acc[k][1];
    }
    float t = 0.0f;
    #pragma unroll
    for (int sg = 0; sg < 8; ++sg) t += sT[sg * 72 + lane];
    return t;
}

// ---- fused prep: embB cast, both weight packs, outmax init, gcur zero ----
__device__ __forceinline__ void prepW_body(const float* __restrict__ Wa,
                                           const float* __restrict__ Wb,
                                           int mode, u16* __restrict__ Wpk, int idx) {
    int fid = idx >> 6, lane = idx & 63;
    int cT = fid >> 2, ks = fid & 3;
    int quad = lane >> 4, l16 = lane & 15;
    int n = cT * 16 + l16;
    u16x8 v;
    #pragma unroll
    for (int j = 0; j < 8; ++j) {
        int k = ks * 32 + quad * 8 + j;
        float f = (mode == 0) ? (k < 64 ? Wa[k * 128 + n] : Wb[(k - 64) * 128 + n])
                              : (n < 64 ? Wa[k * 64 + n] : Wb[k * 64 + (n - 64)]);
        v[j] = f2bf(f);
    }
    *(u16x8*)(Wpk + idx * 8) = v;
}

__global__ __launch_bounds__(256) void k_prep(
        const float* __restrict__ emb, u16* __restrict__ embB,
        const float* __restrict__ W1l, const float* __restrict__ W1r,
        u16* __restrict__ Wpk1,
        const float* __restrict__ W2l, const float* __restrict__ W2r,
        u16* __restrict__ Wpk2, unsigned* __restrict__ om,
        int* __restrict__ gcur) {
    int bid = blockIdx.x, t = threadIdx.x;
    if (bid < 2500) {
        int i = bid * 256 + t;
        if (i < VOCAB * 64) embB[i] = f2bf(emb[i]);
    } else if (bid < 2508) {
        prepW_body(W1l, W1r, 0, Wpk1, (bid - 2500) * 256 + t);
    } else if (bid < 2516) {
        prepW_body(W2l, W2r, 1, Wpk2, (bid - 2508) * 256 + t);
    } else if (bid < 2644) {
        int i = (bid - 2516) * 256 + t;
        if (i < NG * 64) om[i] = 0x007FFFFFu;  // encF(-inf)
    } else {
        if (t < NBUK) gcur[t] = 0;
    }
}

// ---- pass 1: partition edges into 256 dst-range buckets (LDS counting sort/tile) ----
// entry = dstlocal(9) | src(17)
__global__ __launch_bounds__(256) void k_bucket(const int* __restrict__ ei,
                                                int* __restrict__ gcur,
                                                unsigned* __restrict__ gbuf) {
    __shared__ int cnt[NBUK];
    __shared__ int start[NBUK];
    __shared__ int gbase[NBUK];
    __shared__ int wsum[4];
    __shared__ unsigned buf[TILE];
    __shared__ unsigned char bkt[TILE];
    const int t = threadIdx.x;
    const int e0 = blockIdx.x * (NE / 256);   // 6250 edges per block
    const int e1 = e0 + (NE / 256);
    for (int tb = e0; tb < e1; tb += TILE) {
        const int tc = min(TILE, e1 - tb);
        cnt[t] = 0;
        __syncthreads();
        // phase A: load + rank within tile
        unsigned ent[TILE / 256];
        unsigned char eb[TILE / 256];
        u16 rk[TILE / 256];
        int nm = 0;
        for (int i = t; i < tc; i += 256) {
            int dst = ei[NE + tb + i];
            int src = ei[tb + i];
            unsigned b = (unsigned)dst / BSZ;
            unsigned dl = (unsigned)dst - b * BSZ;
            ent[nm] = (dl << 17) | (unsigned)src;
            eb[nm] = (unsigned char)b;
            rk[nm] = (u16)atomicAdd(&cnt[b], 1);
            ++nm;
        }
        __syncthreads();
        // phase B: 4-wave shuffle scan of 256 counts + global reservation
        {
            int c = cnt[t];
            int s = c;
            #pragma unroll
            for (int d = 1; d < 64; d <<= 1) {
                int v = __shfl_up(s, d, 64);
                if ((t & 63) >= d) s += v;
            }
            if ((t & 63) == 63) wsum[t >> 6] = s;
            __syncthreads();
            int pre = 0;
            #pragma unroll
            for (int w = 0; w < 4; ++w) pre += (w < (t >> 6)) ? wsum[w] : 0;
            start[t] = pre + s - c;
            gbase[t] = atomicAdd(&gcur[t], c);
        }
        __syncthreads();
        // phase C: place into bucket-sorted LDS buffer
        for (int k = 0; k < nm; ++k) {
            int pos = start[eb[k]] + rk[k];
            buf[pos] = ent[k];
            bkt[pos] = eb[k];
        }
        __syncthreads();
        // phase D: coalesced flush
        for (int i = t; i < tc; i += 256) {
            unsigned b = bkt[i];
            gbuf[(size_t)b * CAP + gbase[b] + (i - start[b])] = buf[i];
        }
        __syncthreads();
    }
}

// ---- pass 2: per-bucket histogram -> wave scan -> offsets -> fill (1 block/bucket) ----
// csr entry = src | (x[src] << 17)
__global__ __launch_bounds__(512) void k_csr(const unsigned* __restrict__ gbuf,
                                             const int* __restrict__ gcur,
                                             const int* __restrict__ x,
                                             int* __restrict__ off,
                                             int* __restrict__ csr) {
    __shared__ int hist[BSZ];
    __shared__ int curL[BSZ];
    __shared__ int wsum[8];
    __shared__ int sred[8];
    const int b = blockIdx.x, t = threadIdx.x;
    if (t < BSZ) hist[t] = 0;
    __syncthreads();
    const int size = gcur[b];
    const unsigned* gb = gbuf + (size_t)b * CAP;
    for (int i = t; i < size; i += 512)
        atomicAdd(&hist[gb[i] >> 17], 1);
    // bucket global base = sum gcur[0..b) (independent of hist)
    {
        int v = (t < 256 && t < b) ? gcur[t] : 0;
        #pragma unroll
        for (int d = 32; d > 0; d >>= 1) v += __shfl_down(v, d, 64);
        if ((t & 63) == 0) sred[t >> 6] = v;
    }
    __syncthreads();
    const int gbase = sred[0] + sred[1] + sred[2] + sred[3];
    // single-pass shuffle scan over hist[0..BSZ)
    int h = (t < BSZ) ? hist[t] : 0;
    int s = h;
    #pragma unroll
    for (int d = 1; d < 64; d <<= 1) {
        int v = __shfl_up(s, d, 64);
        if ((t & 63) >= d) s += v;
    }
    if ((t & 63) == 63) wsum[t >> 6] = s;
    __syncthreads();
    int pre = 0;
    #pragma unroll
    for (int w = 0; w < 7; ++w) pre += (w < (t >> 6)) ? wsum[w] : 0;
    if (t < BSZ) {
        int ex = gbase + pre + s - h;  // exclusive global offset
        curL[t] = ex;
        int g0 = b * BSZ;
        if (g0 + t <= NN) off[g0 + t] = ex;  // covers off[NN]=NE
    }
    __syncthreads();
    for (int i = t; i < size; i += 512) {
        unsigned ent = gb[i];
        int src = (int)(ent & 0x1FFFFu);
        int dl  = (int)(ent >> 17);
        int pos = atomicAdd(&curL[dl], 1);
        csr[pos] = src | (x[src] << 17);
    }
}

// ---- gather-mean of emb[x[src]] into cols 0..63 of A1; own emb into 64..127 ----
__global__ __launch_bounds__(256) void k_gather1(const int* __restrict__ off,
                                                 const int* __restrict__ csr,
                                                 const int* __restrict__ x,
                                                 const u16* __restrict__ embB,
                                                 u16* __restrict__ A1) {
    __shared__ float sT[4][576];
    int wv = threadIdx.x >> 6, lane = threadIdx.x & 63;
    for (int grp = blockIdx.x; grp * 4 < NN; grp += gridDim.x) {
        int wid = grp * 4 + wv;  // NN % 4 == 0
        int beg = off[wid], end = off[wid + 1];
        f32x2 acc[4] = {{0.f, 0.f}, {0.f, 0.f}, {0.f, 0.f}, {0.f, 0.f}};
        gather8<true>(csr, beg, end, embB, lane, acc);
        float t = reduce_dim(acc, sT[wv], lane);
        A1[wid * 128 + lane] = f2bf(t / fmaxf((float)(end - beg), 1.0f));
        A1[wid * 128 + 64 + lane] = embB[x[wid] * 64 + lane];  // fused embed
    }
}

// ---- fused GEMM1+GEMM2 through LDS: H1 = relu(A1@W1+b1); [P|Q] = H1@W2 ----
__global__ __launch_bounds__(256) void k_gemm12(
        const u16* __restrict__ A1, const u16* __restrict__ Wpk1,
        const u16* __restrict__ Wpk2, const float* __restrict__ b1,
        u16* __restrict__ P, u16* __restrict__ Q) {
    __shared__ __align__(16) u16 sH1[64][136];  // pad: 272 B row stride
    int w = threadIdx.x >> 6, lane = threadIdx.x & 63;
    int quad = lane >> 4, l16 = lane & 15;
    u16x8 bf1[2][4], bf2[2][4];
    #pragma unroll
    for (int ct = 0; ct < 2; ++ct)
        #pragma unroll
        for (int ks = 0; ks < 4; ++ks) {
            int fid = (w * 2 + ct) * 4 + ks;
            bf1[ct][ks] = *(const u16x8*)(Wpk1 + (fid * 64 + lane) * 8);
            bf2[ct][ks] = *(const u16x8*)(Wpk2 + (fid * 64 + lane) * 8);
        }
    int r0 = blockIdx.x * 64;
    // stage 1: H1 tile -> LDS
    #pragma unroll
    for (int rt = 0; rt < 4; ++rt) {
        int row = r0 + rt * 16 + l16;
        u16x8 a[4];
        #pragma unroll
        for (int ks = 0; ks < 4; ++ks)
            a[ks] = *(const u16x8*)(A1 + row * 128 + ks * 32 + quad * 8);
        #pragma unroll
        for (int ct = 0; ct < 2; ++ct) {
            f32x4 acc = {0.f, 0.f, 0.f, 0.f};
            #pragma unroll
            for (int ks = 0; ks < 4; ++ks)
                acc = __builtin_amdgcn_mfma_f32_16x16x32_bf16(
                    __builtin_bit_cast(bf16x8, a[ks]),
                    __builtin_bit_cast(bf16x8, bf1[ct][ks]), acc, 0, 0, 0);
            int col = w * 32 + ct * 16 + l16;
            float bias = b1[col];
            int lr = rt * 16 + quad * 4;
            #pragma unroll
            for (int reg = 0; reg < 4; ++reg)
                sH1[lr + reg][col] = f2bf(fmaxf(acc[reg] + bias, 0.f));
        }
    }
    __syncthreads();
    // stage 2: [P|Q] from LDS H1
    #pragma unroll
    for (int rt = 0; rt < 4; ++rt) {
        u16x8 a[4];
        #pragma unroll
        for (int ks = 0; ks < 4; ++ks)
            a[ks] = *(const u16x8*)(&sH1[rt * 16 + l16][ks * 32 + quad * 8]);
        #pragma unroll
        for (int ct = 0; ct < 2; ++ct) {
            f32x4 acc = {0.f, 0.f, 0.f, 0.f};
            #pragma unroll
            for (int ks = 0; ks < 4; ++ks)
                acc = __builtin_amdgcn_mfma_f32_16x16x32_bf16(
                    __builtin_bit_cast(bf16x8, a[ks]),
                    __builtin_bit_cast(bf16x8, bf2[ct][ks]), acc, 0, 0, 0);
            int col = w * 32 + ct * 16 + l16;
            int gr = r0 + rt * 16 + quad * 4;
            u16* dstT = (col < 64) ? P : Q;
            int c = col & 63;
            #pragma unroll
            for (int reg = 0; reg < 4; ++reg)
                dstT[(gr + reg) * 64 + c] = f2bf(acc[reg]);
        }
    }
}

// ---- final: h2 = mean_agg(P) + b2 + Q, segment-max into om ----
__global__ __launch_bounds__(256) void k_final(const int* __restrict__ off,
                                               const int* __restrict__ csr,
                                               const u16* __restrict__ P,
                                               const u16* __restrict__ Q,
                                               const float* __restrict__ b2,
                                               const int* __restrict__ batch,
                                               unsigned* __restrict__ om) {
    __shared__ float sT[4][576];
    __shared__ float sR[4][64];
    __shared__ int sG[4];
    int wv = threadIdx.x >> 6, lane = threadIdx.x & 63;
    for (int grp = blockIdx.x; grp * 4 < NN; grp += gridDim.x) {
        int node = grp * 4 + wv;  // NN % 4 == 0
        int beg = off[node], end = off[node + 1];
        f32x2 acc[4] = {{0.f, 0.f}, {0.f, 0.f}, {0.f, 0.f}, {0.f, 0.f}};
        gather8<false>(csr, beg, end, P, lane, acc);
        float t = reduce_dim(acc, sT[wv], lane);
        float r = t / fmaxf((float)(end - beg), 1.0f) + b2[lane]
                + bf2f(Q[node * 64 + lane]);
        int g = batch[node];
        sR[wv][lane] = r;
        if (lane == 0) sG[wv] = g;
        __syncthreads();
        bool leader = (wv == 0) || (sG[wv - 1] != g);
        if (leader) {
            float m = r;
            for (int u = wv + 1; u < 4 && sG[u] == g; ++u) m = fmaxf(m, sR[u][lane]);
            atomicMax(&om[g * 64 + lane], encF(m));
        }
        __syncthreads();
    }
}

__global__ void k_decode(const unsigned* __restrict__ om, float* __restrict__ out) {
    int i = blockIdx.x * blockDim.x + threadIdx.x;
    if (i < NG * 64) out[i] = decF(om[i]);
}

extern "C" void kernel_launch(void* const* d_in, const int* in_sizes, int n_in,
                              void* d_out, int out_size, void* d_ws, size_t ws_size,
                              hipStream_t stream) {
    const int*   x     = (const int*)d_in[0];
    const int*   ei    = (const int*)d_in[1];   // [2, NE] flat: src | dst
    const int*   batch = (const int*)d_in[2];
    // d_in[3] = edge_attr, unused by SAGEConv
    const float* emb   = (const float*)d_in[4];
    const float* W1l   = (const float*)d_in[5];
    const float* b1    = (const float*)d_in[6];
    const float* W1r   = (const float*)d_in[7];
    const float* W2l   = (const float*)d_in[8];
    const float* b2    = (const float*)d_in[9];
    const float* W2r   = (const float*)d_in[10];
    float* out = (float*)d_out;

    // workspace layout (bytes)
    char* p = (char*)d_ws;
    u16* A1   = (u16*)p;               p += (size_t)NP * 128 * 2;  // [agg1 | h0]
    u16* P    = (u16*)p;               p += (size_t)NP * 64 * 2;
    u16* Q    = (u16*)p;               p += (size_t)NP * 64 * 2;
    int* csr  = (int*)p;               p += (size_t)NE * 4;
    unsigned* gbuf = (unsigned*)p;     p += (size_t)NBUK * CAP * 4;
    int* gcur = (int*)p;               p += NBUK * 4;
    int* off  = (int*)p;               p += (size_t)(NN + 1) * 4;
    u16* Wpk1 = (u16*)p;               p += 16384 * 2;
    u16* Wpk2 = (u16*)p;               p += 16384 * 2;
    u16* embB = (u16*)p;               p += (size_t)VOCAB * 64 * 2;
    unsigned* om = (unsigned*)p;

    k_prep<<<2645, 256, 0, stream>>>(emb, embB, W1l, W1r, Wpk1, W2l, W2r, Wpk2,
                                     om, gcur);
    k_bucket<<<256, 256, 0, stream>>>(ei, gcur, gbuf);
    k_csr<<<NBUK, 512, 0, stream>>>(gbuf, gcur, x, off, csr);
    k_gather1<<<2048, 256, 0, stream>>>(off, csr, x, embB, A1);
    k_gemm12<<<NP / 64, 256, 0, stream>>>(A1, Wpk1, Wpk2, b1, P, Q);
    k_final<<<2048, 256, 0, stream>>>(off, csr, P, Q, b2, batch, om);
    k_decode<<<(NG * 64 + 255) / 256, 256, 0, stream>>>(om, out);
}